// Round 12
// baseline (248.481 us; speedup 1.0000x reference)
//
#include <hip/hip_runtime.h>
#include <hip/hip_bf16.h>

// TCFormer dynamic attention, MI355X.
//  k_setup:      weights -> bf16 [n][k] transposes (qwt prescaled); k/v pad zero;
//                conf = -1e30. Small kernel so qwt is ready before k_tokq's q part.
//  k_tokq:       blocks <12544: token2map gather (XCD-swizzled, b=bid&7);
//                blocks >=12544: q GEMM (q_x @ qwt -> qbuf), A staged in LDS,
//                B-frags direct from qwt (L2-resident) -> kernel LDS 17.4KB only.
//                Independent work overlaps under gather latency.
//  k_conv_ln_kv: 4x4/s4 conv as MFMA GEMM (B-frags direct from srwt) + fused
//                LayerNorm -> LDS -> kv projection scatter; + conf pool
//  k_attn:       flash attn, 256 thr, 1 head/block, 128 q rows, K/V LDS
//                double-buffer, single barrier/tile, swapped QK^T, conf as direct
//                MFMA C-operand, v_exp_f32 softmax, l via ones-column MFMA,
//                XCD swizzle (each XCD owns 2 bh).
//  k_proj:       attbuf @ proj_w + proj_b -> f32 out; B-frags direct from pwt.
//  REGISTER LESSON (R7+R10): launch_bounds 2nd arg is waves/EU. k_attn needs
//  ~84 VGPR + ~40 AGPR; 4 waves/EU caps the unified file at 128 -> spills
//  (~600MB scratch traffic, 3x slower). (256,3) is its ceiling.

#define NBATCH 8
#define NQTOK  12544
#define NSP    832
#define LOG2E  1.4426950408889634f
#define QSCALE (0.125f * LOG2E)

typedef __attribute__((ext_vector_type(8))) short bf8;
typedef __attribute__((ext_vector_type(4))) float f4;
typedef __attribute__((ext_vector_type(4))) unsigned short u16x4;
typedef __attribute__((ext_vector_type(2))) unsigned int u32x2;

#define MFMA16(a, b, c) __builtin_amdgcn_mfma_f32_16x16x32_bf16((a), (b), (c), 0, 0, 0)

#if __has_builtin(__builtin_amdgcn_exp2f)
#define EXP2(x) __builtin_amdgcn_exp2f(x)
#else
#define EXP2(x) exp2f(x)
#endif

__device__ __forceinline__ unsigned short f2b(float x) {
  union { float f; unsigned u; } v; v.f = x;
  unsigned r = v.u + 0x7FFFu + ((v.u >> 16) & 1u);
  return (unsigned short)(r >> 16);
}

__device__ __forceinline__ unsigned pk2(float lo, float hi) {
  float2 t; t.x = lo; t.y = hi;
  __hip_bfloat162 bb = __float22bfloat162_rn(t);
  union { __hip_bfloat162 b; unsigned u; } v; v.b = bb;
  return v.u;
}

// Row-layout reg pairs (rows 16mf+4g+reg, passthrough col l15) -> 8-wide-k frag.
__device__ __forceinline__ bf8 rows2frag(const unsigned W0[2], const unsigned W1[2]) {
  u32x2 r0 = __builtin_amdgcn_permlane32_swap(W0[0], W1[0], false, false);
  u32x2 t02 = __builtin_amdgcn_permlane16_swap(r0.x, r0.y, false, false);
  u32x2 r1 = __builtin_amdgcn_permlane32_swap(W0[1], W1[1], false, false);
  u32x2 t13 = __builtin_amdgcn_permlane16_swap(r1.x, r1.y, false, false);
  union { unsigned u[4]; bf8 v; } pa;
  pa.u[0] = t02.x; pa.u[1] = t13.x; pa.u[2] = t02.y; pa.u[3] = t13.y;
  return pa.v;
}

// lane holds tile[rbase + (lane&15)][kbase + 8*(lane>>4) .. +7]
__device__ __forceinline__ bf8 ldfrag(const unsigned short* t, int stride, int rbase, int kbase) {
  int lane = threadIdx.x & 63;
  return *(const bf8*)(t + (rbase + (lane & 15)) * stride + kbase + ((lane >> 4) << 3));
}

// ---------------- setup ----------------
__global__ void k_setup(const float* __restrict__ qw, const float* __restrict__ kvw,
                        const float* __restrict__ pw, const float* __restrict__ srw,
                        unsigned short* __restrict__ qwt, unsigned short* __restrict__ kvwt,
                        unsigned short* __restrict__ pwt, unsigned short* __restrict__ srwt,
                        unsigned* __restrict__ kb, unsigned* __restrict__ vb,
                        float* __restrict__ conf) {
  int tid = blockIdx.x * 256 + threadIdx.x;
  int nt = gridDim.x * 256;
  for (int i = tid; i < 128 * 128; i += nt) {
    int k = i >> 7, n = i & 127;
    qwt[n * 128 + k] = f2b(qw[k * 128 + n] * QSCALE);
    pwt[n * 128 + k] = f2b(pw[k * 128 + n]);
  }
  for (int i = tid; i < 128 * 256; i += nt) {
    int k = i >> 8, j = i & 255;
    kvwt[j * 128 + k] = f2b(kvw[k * 256 + j]);
  }
  for (int i = tid; i < 128 * 2048; i += nt) {
    int o = i >> 11, kk = i & 2047;
    int p = kk >> 7, c = kk & 127;
    srwt[o * 2048 + kk] = f2b(srw[o * 2048 + c * 16 + p]);
  }
  const int nu = NBATCH * 2 * NSP * 64 / 2;
  for (int i = tid; i < nu; i += nt) { kb[i] = 0u; vb[i] = 0u; }
  for (int i = tid; i < NBATCH * NSP; i += nt) conf[i] = -1e30f;
}

// ---------------- token2map (XCD-swizzled) + fused q GEMM ----------------
__launch_bounds__(256)
__global__ void k_tokq(const float* __restrict__ kv_x, const float* __restrict__ tsc,
                       const int* __restrict__ idxt,
                       unsigned short* __restrict__ kv_map, float* __restrict__ conf_map,
                       const float* __restrict__ q_x, const unsigned short* __restrict__ qwt,
                       unsigned short* __restrict__ qbuf) {
  __shared__ unsigned short At[64 * 136];
  const int tid = threadIdx.x;
  const int bid = blockIdx.x;
  if (bid >= 12544) {                              // q GEMM tail: 1568 blocks
    const int qb = bid - 12544;
    const int lane = tid & 63, w = tid >> 6;
    const int l15 = lane & 15, g = lane >> 4;
    const int r0 = (qb & 7) * NQTOK + (qb >> 3) * 64;   // batch (qb&7) on XCD (qb&7)
#pragma unroll
    for (int j = 0; j < 8; j++) {
      int id = tid + 256 * j;
      int row = id >> 5, c0 = (id & 31) << 2;
      float4 v = *(const float4*)(q_x + (long)(r0 + row) * 128 + c0);
      u16x4 o;
      o[0] = f2b(v.x); o[1] = f2b(v.y); o[2] = f2b(v.z); o[3] = f2b(v.w);
      *(u16x4*)(At + row * 136 + c0) = o;
    }
    __syncthreads();
    const f4 fz = {0.f, 0.f, 0.f, 0.f};
    f4 acc[8];
#pragma unroll
    for (int i = 0; i < 8; i++) acc[i] = fz;
#pragma unroll
    for (int ks = 0; ks < 4; ks++) {
      bf8 a = ldfrag(At, 136, 16 * w, 32 * ks);
#pragma unroll
      for (int nf = 0; nf < 8; nf++) {
        bf8 bb = *(const bf8*)(qwt + (16 * nf + l15) * 128 + 32 * ks + (g << 3));
        acc[nf] = MFMA16(a, bb, acc[nf]);
      }
    }
#pragma unroll
    for (int nf = 0; nf < 8; nf++)
#pragma unroll
      for (int reg = 0; reg < 4; reg++) {
        int r = r0 + 16 * w + 4 * g + reg;
        int b = r / NQTOK, n = r - b * NQTOK;
        int j = 16 * nf + l15;
        int hh = j >> 6, d = j & 63;
        qbuf[((long)(b * 2 + hh) * NQTOK + n) * 64 + d] = f2b(acc[nf][reg]);
      }
    return;
  }
  int b = bid & 7, pos = bid >> 3;                 // 1568 blocks/batch on one XCD
  int hw = pos * 8 + (tid >> 5);
  int cell = b * 12544 + hw;
  int c0 = (tid & 31) << 2;
  int h = hw / 112, w = hw - h * 112;
  const int* it = idxt + b * 50176;
  int t0 = it[(2 * h) * 224 + 2 * w];
  int t1 = it[(2 * h) * 224 + 2 * w + 1];
  int t2 = it[(2 * h + 1) * 224 + 2 * w];
  int t3 = it[(2 * h + 1) * 224 + 2 * w + 1];
  const float* base = kv_x + (long)b * 12544 * 128 + c0;
  const float recip = 1.0f / (4.0f + 1e-6f);
  float4 a0 = *(const float4*)(base + (long)t0 * 128);
  float4 a1 = *(const float4*)(base + (long)t1 * 128);
  float4 a2 = *(const float4*)(base + (long)t2 * 128);
  float4 a3 = *(const float4*)(base + (long)t3 * 128);
  u16x4 o;
  o[0] = f2b((a0.x + a1.x + a2.x + a3.x) * recip);
  o[1] = f2b((a0.y + a1.y + a2.y + a3.y) * recip);
  o[2] = f2b((a0.z + a1.z + a2.z + a3.z) * recip);
  o[3] = f2b((a0.w + a1.w + a2.w + a3.w) * recip);
  *(u16x4*)(kv_map + (long)cell * 128 + c0) = o;
  if ((tid & 31) == 0) {
    const float* ts = tsc + b * 12544;
    conf_map[cell] = (ts[t0] + ts[t1] + ts[t2] + ts[t3]) * recip;
  }
}

// ---------------- conv (patch GEMM, B direct) + LayerNorm + kv projection ----------------
__launch_bounds__(256)
__global__ void k_conv_ln_kv(const unsigned short* __restrict__ kv_map,
                             const unsigned short* __restrict__ srwt,
                             const float* __restrict__ srb, const float* __restrict__ ng,
                             const float* __restrict__ nb,
                             const unsigned short* __restrict__ kvwt,
                             unsigned short* __restrict__ kbuf,
                             unsigned short* __restrict__ vbuf,
                             const float* __restrict__ conf_map, float* __restrict__ conf) {
  __shared__ unsigned short At[64 * 136];
  const int tid = threadIdx.x;
  const int lane = tid & 63, w = tid >> 6;
  const int l15 = lane & 15, g = lane >> 4;
  const int r0 = blockIdx.x * 64;
  if (tid < 64) {
    int pos = r0 + tid;
    int bq = pos / 784, p2 = pos - bq * 784;
    int oh = p2 / 28, ow = p2 - oh * 28;
    float s = 0.f;
#pragma unroll
    for (int kh = 0; kh < 4; kh++)
#pragma unroll
      for (int kw = 0; kw < 4; kw++)
        s += conf_map[bq * 12544 + (4 * oh + kh) * 112 + 4 * ow + kw];
    conf[bq * NSP + p2] = s * (LOG2E / 16.0f);
  }
  const f4 fz = {0.f, 0.f, 0.f, 0.f};
  f4 acc[8];
#pragma unroll
  for (int i = 0; i < 8; i++) acc[i] = fz;

  for (int p = 0; p < 16; p++) {
#pragma unroll
    for (int j = 0; j < 4; j++) {
      int id = tid + 256 * j;
      int row = id >> 4, c0 = (id & 15) << 3;
      int rr = r0 + row;
      int bb = rr / 784, pos = rr - bb * 784;
      int oh = pos / 28, ow = pos - oh * 28;
      long src = ((long)(bb * 12544 + (4 * oh + (p >> 2)) * 112 + 4 * ow + (p & 3))) * 128 + c0;
      *(uint4*)(At + row * 136 + c0) = *(const uint4*)(kv_map + src);
    }
    __syncthreads();
#pragma unroll
    for (int ks = 0; ks < 4; ks++) {
      bf8 a = ldfrag(At, 136, 16 * w, 32 * ks);
#pragma unroll
      for (int nf = 0; nf < 8; nf++) {
        bf8 bb = *(const bf8*)(srwt + (16 * nf + l15) * 2048 + p * 128 + 32 * ks + (g << 3));
        acc[nf] = MFMA16(a, bb, acc[nf]);
      }
    }
    __syncthreads();
  }
  float sum_[4] = {0.f, 0.f, 0.f, 0.f}, sq_[4] = {0.f, 0.f, 0.f, 0.f};
#pragma unroll
  for (int nf = 0; nf < 8; nf++) {
    float bias = srb[16 * nf + l15];
#pragma unroll
    for (int reg = 0; reg < 4; reg++) {
      float v = acc[nf][reg] + bias;
      acc[nf][reg] = v;
      sum_[reg] += v;
      sq_[reg] += v * v;
    }
  }
#pragma unroll
  for (int msk = 1; msk < 16; msk <<= 1)
#pragma unroll
    for (int reg = 0; reg < 4; reg++) {
      sum_[reg] += __shfl_xor(sum_[reg], msk, 64);
      sq_[reg] += __shfl_xor(sq_[reg], msk, 64);
    }
#pragma unroll
  for (int nf = 0; nf < 8; nf++) {
    float gc = ng[16 * nf + l15], bc = nb[16 * nf + l15];
#pragma unroll
    for (int reg = 0; reg < 4; reg++) {
      float mean = sum_[reg] * (1.0f / 128.0f);
      float var = sq_[reg] * (1.0f / 128.0f) - mean * mean;
      float v = (acc[nf][reg] - mean) * rsqrtf(var + 1e-5f) * gc + bc;
      At[(16 * w + 4 * g + reg) * 136 + 16 * nf + l15] = f2b(v);
    }
  }
  __syncthreads();
  f4 acc2[16];
#pragma unroll
  for (int i = 0; i < 16; i++) acc2[i] = fz;
#pragma unroll
  for (int ks = 0; ks < 4; ks++) {
    bf8 a = ldfrag(At, 136, 16 * w, 32 * ks);
#pragma unroll
    for (int nf = 0; nf < 16; nf++) {
      bf8 bb = *(const bf8*)(kvwt + (16 * nf + l15) * 128 + 32 * ks + (g << 3));
      acc2[nf] = MFMA16(a, bb, acc2[nf]);
    }
  }
#pragma unroll
  for (int nf = 0; nf < 16; nf++)
#pragma unroll
    for (int reg = 0; reg < 4; reg++) {
      int r = r0 + 16 * w + 4 * g + reg;
      int b = r / 784, ns = r - b * 784;
      int j = 16 * nf + l15;
      int sel = j >> 7, hh = (j >> 6) & 1, d = j & 63;
      unsigned short val = f2b(acc2[nf][reg]);
      if (sel == 0) kbuf[((long)(b * 2 + hh) * NSP + ns) * 64 + d] = val;
      else          vbuf[((long)(b * 2 + hh) * 64 + d) * NSP + ns] = val;
    }
}

// ---------------- flash attention (XCD swizzle, conf as direct C-operand) ----------------
__launch_bounds__(256, 3)
__global__ void k_attn(const unsigned short* __restrict__ qbuf,
                       const unsigned short* __restrict__ kbuf,
                       const unsigned short* __restrict__ vbuf,
                       const float* __restrict__ conf,
                       unsigned short* __restrict__ attbuf) {
  __shared__ unsigned short Kt[2][64 * 72];   // [kv][d], stride 72
  __shared__ unsigned short Vt[2][64 * 72];   // [d][kv], stride 72
  const int tid = threadIdx.x;
  const int lane = tid & 63, w = tid >> 6;
  const int l15 = lane & 15, g = lane >> 4;
  // XCD swizzle: grid 1568 = 8 XCDs x 196; each XCD owns 2 bh (K/V L2-resident)
  const int bid = blockIdx.x;
  const int xcd = bid & 7, idx = bid >> 3;    // idx 0..195
  const int sub = idx / 98;                   // 0..1
  const int xb = idx - sub * 98;
  const int bhid = xcd * 2 + sub;             // 0..15
  const int b = bhid >> 1, h = bhid & 1;
  const int bh = b * 2 + h;
  const int q0 = xb * 128 + 32 * w;           // this wave's 32 q rows

  const unsigned short* qsrc = qbuf + ((long)bh * NQTOK + q0) * 64;
  bf8 qf[2][2];
#pragma unroll
  for (int mr = 0; mr < 2; mr++)
#pragma unroll
    for (int ks = 0; ks < 2; ks++)
      qf[mr][ks] = *(const bf8*)(qsrc + (16 * mr + l15) * 64 + 32 * ks + (g << 3));

  const int srow = tid >> 2;
  const int scol = (tid & 3) << 4;
  const unsigned short* kg = kbuf + (long)bh * NSP * 64 + srow * 64 + scol;
  const unsigned short* vg = vbuf + (long)bh * 64 * NSP + (long)srow * NSP + scol;
  unsigned short* klds = &Kt[0][0] + srow * 72 + scol;
  unsigned short* vlds = &Vt[0][0] + srow * 72 + scol;

  uint4 kr0, kr1, vr0, vr1;
#define ISSUE(T)                                                   \
  do {                                                             \
    const unsigned short* kp_ = kg + (long)(T) * 4096;             \
    const unsigned short* vp_ = vg + (T) * 64;                     \
    kr0 = *(const uint4*)(kp_);                                    \
    kr1 = *(const uint4*)(kp_ + 8);                                \
    vr0 = *(const uint4*)(vp_);                                    \
    vr1 = *(const uint4*)(vp_ + 8);                                \
  } while (0)
#define STWRITE(BUF)                                               \
  do {                                                             \
    unsigned short* kd_ = klds + (BUF) * 4608;                     \
    unsigned short* vd_ = vlds + (BUF) * 4608;                     \
    *(uint4*)kd_ = kr0;  *(uint4*)(kd_ + 8) = kr1;                 \
    *(uint4*)vd_ = vr0;  *(uint4*)(vd_ + 8) = vr1;                 \
  } while (0)

  ISSUE(0);
  STWRITE(0);
  ISSUE(1);
  __syncthreads();

  const f4 fz = {0.f, 0.f, 0.f, 0.f};
  f4 ao[2][4], aol[2];
#pragma unroll
  for (int mr = 0; mr < 2; mr++) {
    aol[mr] = fz;
#pragma unroll
    for (int i = 0; i < 4; i++) ao[mr][i] = fz;
  }
  const short on = (short)0x3F80;                  // bf16 1.0
  const bf8 onesf = {on, on, on, on, on, on, on, on};
  const float* confb = conf + b * NSP;

#pragma unroll 2
  for (int t = 0; t < 13; t++) {
    const int cur = t & 1;
    const unsigned short* KtB = &Kt[cur][0];
    const unsigned short* VtB = &Vt[cur][0];
    bf8 kf[4][2];
#pragma unroll
    for (int mf = 0; mf < 4; mf++)
#pragma unroll
      for (int ks = 0; ks < 2; ks++)
        kf[mf][ks] = ldfrag(KtB, 72, 16 * mf, 32 * ks);
    bf8 vf[4][2];
#pragma unroll
    for (int nfd = 0; nfd < 4; nfd++)
#pragma unroll
      for (int ks = 0; ks < 2; ks++)
        vf[nfd][ks] = ldfrag(VtB, 72, 16 * nfd, 32 * ks);
    // conf as MFMA C-operand: C row = kv = 16mf+4g+reg, q-uniform across cols
    f4 cvi[4];
#pragma unroll
    for (int mf = 0; mf < 4; mf++) {
      float4 cv = *(const float4*)(confb + t * 64 + 16 * mf + 4 * g);
      cvi[mf][0] = cv.x; cvi[mf][1] = cv.y; cvi[mf][2] = cv.z; cvi[mf][3] = cv.w;
    }
#pragma unroll
    for (int mr = 0; mr < 2; mr++) {
      f4 s_[4];
#pragma unroll
      for (int mf = 0; mf < 4; mf++)
        s_[mf] = MFMA16(kf[mf][0], qf[mr][0], cvi[mf]);   // C-in = conf, no copy
#pragma unroll
      for (int mf = 0; mf < 4; mf++)
        s_[mf] = MFMA16(kf[mf][1], qf[mr][1], s_[mf]);
      unsigned W[4][2];
#pragma unroll
      for (int mf = 0; mf < 4; mf++) {
        float p0 = EXP2(s_[mf][0]);
        float p1 = EXP2(s_[mf][1]);
        float p2 = EXP2(s_[mf][2]);
        float p3 = EXP2(s_[mf][3]);
        W[mf][0] = pk2(p0, p1);
        W[mf][1] = pk2(p2, p3);
      }
#pragma unroll
      for (int ks = 0; ks < 2; ks++) {
        bf8 pa = rows2frag(W[2 * ks], W[2 * ks + 1]);
        aol[mr] = MFMA16(pa, onesf, aol[mr]);
#pragma unroll
        for (int nfd = 0; nfd < 4; nfd++)
          ao[mr][nfd] = MFMA16(pa, vf[nfd][ks], ao[mr][nfd]);
      }
    }
    if (t < 12) STWRITE(cur ^ 1);
    if (t < 11) ISSUE(t + 2);
    __syncthreads();
  }
#undef ISSUE
#undef STWRITE
#pragma unroll
  for (int mr = 0; mr < 2; mr++) {
    float inv[4];
#pragma unroll
    for (int reg = 0; reg < 4; reg++) inv[reg] = 1.0f / aol[mr][reg];
#pragma unroll
    for (int nfd = 0; nfd < 4; nfd++)
#pragma unroll
      for (int reg = 0; reg < 4; reg++) {
        int n = q0 + 16 * mr + 4 * g + reg;
        int col = h * 64 + 16 * nfd + l15;
        attbuf[((long)b * NQTOK + n) * 128 + col] = f2b(ao[mr][nfd][reg] * inv[reg]);
      }
  }
}

// ---------------- final projection (XCD-swizzled, B direct from pwt) ----------------
__launch_bounds__(256)
__global__ void k_proj(const unsigned short* __restrict__ attbuf,
                       const unsigned short* __restrict__ pwt,
                       const float* __restrict__ pb, float* __restrict__ out) {
  __shared__ unsigned short At[64 * 136];
  const int tid = threadIdx.x;
  const int lane = tid & 63, w = tid >> 6;
  const int l15 = lane & 15, g = lane >> 4;
  const int bid = blockIdx.x;
  const int r0 = (bid & 7) * NQTOK + (bid >> 3) * 64;   // batch (bid&7) on XCD (bid&7)
#pragma unroll
  for (int j = 0; j < 4; j++) {
    int id = tid + 256 * j;
    int row = id >> 4, c0 = (id & 15) << 3;
    *(uint4*)(At + row * 136 + c0) = *(const uint4*)(attbuf + (long)(r0 + row) * 128 + c0);
  }
  __syncthreads();
  const f4 fz = {0.f, 0.f, 0.f, 0.f};
  f4 acc[8];
#pragma unroll
  for (int i = 0; i < 8; i++) acc[i] = fz;
#pragma unroll
  for (int ks = 0; ks < 4; ks++) {
    bf8 a = ldfrag(At, 136, 16 * w, 32 * ks);
#pragma unroll
    for (int nf = 0; nf < 8; nf++) {
      bf8 bb = *(const bf8*)(pwt + (16 * nf + l15) * 128 + 32 * ks + (g << 3));
      acc[nf] = MFMA16(a, bb, acc[nf]);
    }
  }
#pragma unroll
  for (int nf = 0; nf < 8; nf++) {
    float bias = pb[16 * nf + l15];
#pragma unroll
    for (int reg = 0; reg < 4; reg++) {
      int r = r0 + 16 * w + 4 * g + reg;
      out[(long)r * 128 + 16 * nf + l15] = acc[nf][reg] + bias;
    }
  }
}

extern "C" void kernel_launch(void* const* d_in, const int* in_sizes, int n_in,
                              void* d_out, int out_size, void* d_ws, size_t ws_size,
                              hipStream_t stream) {
  const float* q_x  = (const float*)d_in[0];
  const float* kv_x = (const float*)d_in[1];
  const float* tsc  = (const float*)d_in[2];
  const int*   idxt = (const int*)d_in[3];
  const float* q_w  = (const float*)d_in[8];
  const float* kv_w = (const float*)d_in[9];
  const float* pw   = (const float*)d_in[10];
  const float* pb   = (const float*)d_in[11];
  const float* srw  = (const float*)d_in[12];
  const float* srb  = (const float*)d_in[13];
  const float* ng   = (const float*)d_in[14];
  const float* nb   = (const float*)d_in[15];
  float* outp = (float*)d_out;

  char* ws = (char*)d_ws;
  size_t off = 0;
  auto take = [&](size_t bytes) {
    char* p = ws + off;
    off += (bytes + 255) & ~(size_t)255;
    return p;
  };
  unsigned short* qwt   = (unsigned short*)take(128 * 128 * 2);
  unsigned short* pwt   = (unsigned short*)take(128 * 128 * 2);
  unsigned short* kvwt  = (unsigned short*)take(256 * 128 * 2);
  unsigned short* srwt  = (unsigned short*)take(128 * 2048 * 2);
  unsigned short* kvmap = (unsigned short*)take((size_t)NBATCH * 12544 * 128 * 2);
  float* conf_map       = (float*)take((size_t)NBATCH * 12544 * 4);
  unsigned short* kbuf  = (unsigned short*)take((size_t)NBATCH * 2 * NSP * 64 * 2);
  unsigned short* vbuf  = (unsigned short*)take((size_t)NBATCH * 2 * NSP * 64 * 2);
  float* conf           = (float*)take((size_t)NBATCH * NSP * 4);
  unsigned short* qbuf  = (unsigned short*)take((size_t)NBATCH * 2 * NQTOK * 64 * 2);
  unsigned short* attbuf = kvmap;  // kv_map dead after k_conv_ln_kv

  k_setup<<<256, 256, 0, stream>>>(q_w, kv_w, pw, srw, qwt, kvwt, pwt, srwt,
                                   (unsigned*)kbuf, (unsigned*)vbuf, conf);
  k_tokq<<<14112, 256, 0, stream>>>(kv_x, tsc, idxt, kvmap, conf_map,
                                    q_x, qwt, qbuf);
  k_conv_ln_kv<<<98, 256, 0, stream>>>(kvmap, srwt, srb, ng, nb, kvwt, kbuf, vbuf,
                                       conf_map, conf);
  k_attn<<<1568, 256, 0, stream>>>(qbuf, kbuf, vbuf, conf, attbuf);
  k_proj<<<1568, 256, 0, stream>>>(attbuf, pwt, pb, outp);
}

// Round 13
// 247.382 us; speedup vs baseline: 1.0044x; 1.0044x over previous
//
#include <hip/hip_runtime.h>
#include <hip/hip_bf16.h>

// TCFormer dynamic attention, MI355X.
//  k_setup:      weights -> bf16 [n][k] transposes (qwt prescaled); k/v pad zero;
//                conf = -1e30.
//  k_token2map:  gather-average 4 tokens/cell -> kv_map bf16, conf_map f32.
//                XCD-swizzled (b=bid&7). LDS-FREE, standalone: R12 showed fusing
//                this latency-bound gather into an LDS-carrying kernel halves its
//                occupancy and doubles its time.
//  k_conv_ln_kv: 4x4/s4 conv as MFMA GEMM (B-frags direct from srwt) + fused
//                LayerNorm -> LDS -> kv projection scatter; + conf pool
//  k_q:          q_x @ qwt -> qbuf; A staged in LDS (17.4KB), B direct from qwt.
//  k_attn:       flash attn, 256 thr, 1 head/block, 128 q rows, K/V LDS
//                double-buffer, single barrier/tile, swapped QK^T, conf as direct
//                MFMA C-operand, v_exp_f32 softmax, l via ones-column MFMA,
//                XCD swizzle (each XCD owns 2 bh).
//  k_proj:       attbuf @ proj_w + proj_b -> f32 out; B direct from pwt.
//  REGISTER LESSON (R7+R10): launch_bounds 2nd arg is waves/EU. k_attn needs
//  ~84 VGPR + ~40 AGPR; 4 waves/EU caps the unified file at 128 -> spills.
//  (256,3) is its ceiling.
//  FUSION LESSON (R12): don't fuse resource-light latency-bound kernels into
//  resource-heavy ones - static LDS/VGPR tax kills the light kernel's occupancy.

#define NBATCH 8
#define NQTOK  12544
#define NSP    832
#define LOG2E  1.4426950408889634f
#define QSCALE (0.125f * LOG2E)

typedef __attribute__((ext_vector_type(8))) short bf8;
typedef __attribute__((ext_vector_type(4))) float f4;
typedef __attribute__((ext_vector_type(4))) unsigned short u16x4;
typedef __attribute__((ext_vector_type(2))) unsigned int u32x2;

#define MFMA16(a, b, c) __builtin_amdgcn_mfma_f32_16x16x32_bf16((a), (b), (c), 0, 0, 0)

#if __has_builtin(__builtin_amdgcn_exp2f)
#define EXP2(x) __builtin_amdgcn_exp2f(x)
#else
#define EXP2(x) exp2f(x)
#endif

__device__ __forceinline__ unsigned short f2b(float x) {
  union { float f; unsigned u; } v; v.f = x;
  unsigned r = v.u + 0x7FFFu + ((v.u >> 16) & 1u);
  return (unsigned short)(r >> 16);
}

__device__ __forceinline__ unsigned pk2(float lo, float hi) {
  float2 t; t.x = lo; t.y = hi;
  __hip_bfloat162 bb = __float22bfloat162_rn(t);
  union { __hip_bfloat162 b; unsigned u; } v; v.b = bb;
  return v.u;
}

// Row-layout reg pairs (rows 16mf+4g+reg, passthrough col l15) -> 8-wide-k frag.
__device__ __forceinline__ bf8 rows2frag(const unsigned W0[2], const unsigned W1[2]) {
  u32x2 r0 = __builtin_amdgcn_permlane32_swap(W0[0], W1[0], false, false);
  u32x2 t02 = __builtin_amdgcn_permlane16_swap(r0.x, r0.y, false, false);
  u32x2 r1 = __builtin_amdgcn_permlane32_swap(W0[1], W1[1], false, false);
  u32x2 t13 = __builtin_amdgcn_permlane16_swap(r1.x, r1.y, false, false);
  union { unsigned u[4]; bf8 v; } pa;
  pa.u[0] = t02.x; pa.u[1] = t13.x; pa.u[2] = t02.y; pa.u[3] = t13.y;
  return pa.v;
}

// lane holds tile[rbase + (lane&15)][kbase + 8*(lane>>4) .. +7]
__device__ __forceinline__ bf8 ldfrag(const unsigned short* t, int stride, int rbase, int kbase) {
  int lane = threadIdx.x & 63;
  return *(const bf8*)(t + (rbase + (lane & 15)) * stride + kbase + ((lane >> 4) << 3));
}

// ---------------- setup ----------------
__global__ void k_setup(const float* __restrict__ qw, const float* __restrict__ kvw,
                        const float* __restrict__ pw, const float* __restrict__ srw,
                        unsigned short* __restrict__ qwt, unsigned short* __restrict__ kvwt,
                        unsigned short* __restrict__ pwt, unsigned short* __restrict__ srwt,
                        unsigned* __restrict__ kb, unsigned* __restrict__ vb,
                        float* __restrict__ conf) {
  int tid = blockIdx.x * 256 + threadIdx.x;
  int nt = gridDim.x * 256;
  for (int i = tid; i < 128 * 128; i += nt) {
    int k = i >> 7, n = i & 127;
    qwt[n * 128 + k] = f2b(qw[k * 128 + n] * QSCALE);
    pwt[n * 128 + k] = f2b(pw[k * 128 + n]);
  }
  for (int i = tid; i < 128 * 256; i += nt) {
    int k = i >> 8, j = i & 255;
    kvwt[j * 128 + k] = f2b(kvw[k * 256 + j]);
  }
  for (int i = tid; i < 128 * 2048; i += nt) {
    int o = i >> 11, kk = i & 2047;
    int p = kk >> 7, c = kk & 127;
    srwt[o * 2048 + kk] = f2b(srw[o * 2048 + c * 16 + p]);
  }
  const int nu = NBATCH * 2 * NSP * 64 / 2;
  for (int i = tid; i < nu; i += nt) { kb[i] = 0u; vb[i] = 0u; }
  for (int i = tid; i < NBATCH * NSP; i += nt) conf[i] = -1e30f;
}

// ---------------- token2map (XCD-swizzled, LDS-free) ----------------
__global__ void k_token2map(const float* __restrict__ kv_x, const float* __restrict__ tsc,
                            const int* __restrict__ idxt,
                            unsigned short* __restrict__ kv_map, float* __restrict__ conf_map) {
  int tid = threadIdx.x;
  int bid = blockIdx.x;
  int b = bid & 7, pos = bid >> 3;                 // 1568 blocks/batch on one XCD
  int hw = pos * 8 + (tid >> 5);
  int cell = b * 12544 + hw;
  int c0 = (tid & 31) << 2;
  int h = hw / 112, w = hw - h * 112;
  const int* it = idxt + b * 50176;
  int t0 = it[(2 * h) * 224 + 2 * w];
  int t1 = it[(2 * h) * 224 + 2 * w + 1];
  int t2 = it[(2 * h + 1) * 224 + 2 * w];
  int t3 = it[(2 * h + 1) * 224 + 2 * w + 1];
  const float* base = kv_x + (long)b * 12544 * 128 + c0;
  const float recip = 1.0f / (4.0f + 1e-6f);
  float4 a0 = *(const float4*)(base + (long)t0 * 128);
  float4 a1 = *(const float4*)(base + (long)t1 * 128);
  float4 a2 = *(const float4*)(base + (long)t2 * 128);
  float4 a3 = *(const float4*)(base + (long)t3 * 128);
  u16x4 o;
  o[0] = f2b((a0.x + a1.x + a2.x + a3.x) * recip);
  o[1] = f2b((a0.y + a1.y + a2.y + a3.y) * recip);
  o[2] = f2b((a0.z + a1.z + a2.z + a3.z) * recip);
  o[3] = f2b((a0.w + a1.w + a2.w + a3.w) * recip);
  *(u16x4*)(kv_map + (long)cell * 128 + c0) = o;
  if ((tid & 31) == 0) {
    const float* ts = tsc + b * 12544;
    conf_map[cell] = (ts[t0] + ts[t1] + ts[t2] + ts[t3]) * recip;
  }
}

// ---------------- conv (patch GEMM, B direct) + LayerNorm + kv projection ----------------
__launch_bounds__(256)
__global__ void k_conv_ln_kv(const unsigned short* __restrict__ kv_map,
                             const unsigned short* __restrict__ srwt,
                             const float* __restrict__ srb, const float* __restrict__ ng,
                             const float* __restrict__ nb,
                             const unsigned short* __restrict__ kvwt,
                             unsigned short* __restrict__ kbuf,
                             unsigned short* __restrict__ vbuf,
                             const float* __restrict__ conf_map, float* __restrict__ conf) {
  __shared__ unsigned short At[64 * 136];
  const int tid = threadIdx.x;
  const int lane = tid & 63, w = tid >> 6;
  const int l15 = lane & 15, g = lane >> 4;
  const int r0 = blockIdx.x * 64;
  if (tid < 64) {
    int pos = r0 + tid;
    int bq = pos / 784, p2 = pos - bq * 784;
    int oh = p2 / 28, ow = p2 - oh * 28;
    float s = 0.f;
#pragma unroll
    for (int kh = 0; kh < 4; kh++)
#pragma unroll
      for (int kw = 0; kw < 4; kw++)
        s += conf_map[bq * 12544 + (4 * oh + kh) * 112 + 4 * ow + kw];
    conf[bq * NSP + p2] = s * (LOG2E / 16.0f);
  }
  const f4 fz = {0.f, 0.f, 0.f, 0.f};
  f4 acc[8];
#pragma unroll
  for (int i = 0; i < 8; i++) acc[i] = fz;

  for (int p = 0; p < 16; p++) {
#pragma unroll
    for (int j = 0; j < 4; j++) {
      int id = tid + 256 * j;
      int row = id >> 4, c0 = (id & 15) << 3;
      int rr = r0 + row;
      int bb = rr / 784, pos = rr - bb * 784;
      int oh = pos / 28, ow = pos - oh * 28;
      long src = ((long)(bb * 12544 + (4 * oh + (p >> 2)) * 112 + 4 * ow + (p & 3))) * 128 + c0;
      *(uint4*)(At + row * 136 + c0) = *(const uint4*)(kv_map + src);
    }
    __syncthreads();
#pragma unroll
    for (int ks = 0; ks < 4; ks++) {
      bf8 a = ldfrag(At, 136, 16 * w, 32 * ks);
#pragma unroll
      for (int nf = 0; nf < 8; nf++) {
        bf8 bb = *(const bf8*)(srwt + (16 * nf + l15) * 2048 + p * 128 + 32 * ks + (g << 3));
        acc[nf] = MFMA16(a, bb, acc[nf]);
      }
    }
    __syncthreads();
  }
  float sum_[4] = {0.f, 0.f, 0.f, 0.f}, sq_[4] = {0.f, 0.f, 0.f, 0.f};
#pragma unroll
  for (int nf = 0; nf < 8; nf++) {
    float bias = srb[16 * nf + l15];
#pragma unroll
    for (int reg = 0; reg < 4; reg++) {
      float v = acc[nf][reg] + bias;
      acc[nf][reg] = v;
      sum_[reg] += v;
      sq_[reg] += v * v;
    }
  }
#pragma unroll
  for (int msk = 1; msk < 16; msk <<= 1)
#pragma unroll
    for (int reg = 0; reg < 4; reg++) {
      sum_[reg] += __shfl_xor(sum_[reg], msk, 64);
      sq_[reg] += __shfl_xor(sq_[reg], msk, 64);
    }
#pragma unroll
  for (int nf = 0; nf < 8; nf++) {
    float gc = ng[16 * nf + l15], bc = nb[16 * nf + l15];
#pragma unroll
    for (int reg = 0; reg < 4; reg++) {
      float mean = sum_[reg] * (1.0f / 128.0f);
      float var = sq_[reg] * (1.0f / 128.0f) - mean * mean;
      float v = (acc[nf][reg] - mean) * rsqrtf(var + 1e-5f) * gc + bc;
      At[(16 * w + 4 * g + reg) * 136 + 16 * nf + l15] = f2b(v);
    }
  }
  __syncthreads();
  f4 acc2[16];
#pragma unroll
  for (int i = 0; i < 16; i++) acc2[i] = fz;
#pragma unroll
  for (int ks = 0; ks < 4; ks++) {
    bf8 a = ldfrag(At, 136, 16 * w, 32 * ks);
#pragma unroll
    for (int nf = 0; nf < 16; nf++) {
      bf8 bb = *(const bf8*)(kvwt + (16 * nf + l15) * 128 + 32 * ks + (g << 3));
      acc2[nf] = MFMA16(a, bb, acc2[nf]);
    }
  }
#pragma unroll
  for (int nf = 0; nf < 16; nf++)
#pragma unroll
    for (int reg = 0; reg < 4; reg++) {
      int r = r0 + 16 * w + 4 * g + reg;
      int b = r / 784, ns = r - b * 784;
      int j = 16 * nf + l15;
      int sel = j >> 7, hh = (j >> 6) & 1, d = j & 63;
      unsigned short val = f2b(acc2[nf][reg]);
      if (sel == 0) kbuf[((long)(b * 2 + hh) * NSP + ns) * 64 + d] = val;
      else          vbuf[((long)(b * 2 + hh) * 64 + d) * NSP + ns] = val;
    }
}

// ---------------- q GEMM (XCD-swizzled, B direct from qwt) ----------------
__launch_bounds__(256)
__global__ void k_q(const float* __restrict__ q_x, const unsigned short* __restrict__ qwt,
                    unsigned short* __restrict__ qbuf) {
  __shared__ unsigned short At[64 * 136];
  const int tid = threadIdx.x;
  const int lane = tid & 63, w = tid >> 6;
  const int l15 = lane & 15, g = lane >> 4;
  const int bid = blockIdx.x;
  const int r0 = (bid & 7) * NQTOK + (bid >> 3) * 64;   // batch (bid&7) on XCD (bid&7)
#pragma unroll
  for (int j = 0; j < 8; j++) {
    int id = tid + 256 * j;
    int row = id >> 5, c0 = (id & 31) << 2;
    float4 v = *(const float4*)(q_x + (long)(r0 + row) * 128 + c0);
    u16x4 o;
    o[0] = f2b(v.x); o[1] = f2b(v.y); o[2] = f2b(v.z); o[3] = f2b(v.w);
    *(u16x4*)(At + row * 136 + c0) = o;
  }
  __syncthreads();
  const f4 fz = {0.f, 0.f, 0.f, 0.f};
  f4 acc[8];
#pragma unroll
  for (int i = 0; i < 8; i++) acc[i] = fz;
#pragma unroll
  for (int ks = 0; ks < 4; ks++) {
    bf8 a = ldfrag(At, 136, 16 * w, 32 * ks);
#pragma unroll
    for (int nf = 0; nf < 8; nf++) {
      bf8 bb = *(const bf8*)(qwt + (16 * nf + l15) * 128 + 32 * ks + (g << 3));
      acc[nf] = MFMA16(a, bb, acc[nf]);
    }
  }
#pragma unroll
  for (int nf = 0; nf < 8; nf++)
#pragma unroll
    for (int reg = 0; reg < 4; reg++) {
      int r = r0 + 16 * w + 4 * g + reg;
      int b = r / NQTOK, n = r - b * NQTOK;
      int j = 16 * nf + l15;
      int hh = j >> 6, d = j & 63;
      qbuf[((long)(b * 2 + hh) * NQTOK + n) * 64 + d] = f2b(acc[nf][reg]);
    }
}

// ---------------- flash attention (XCD swizzle, conf as direct C-operand) ----------------
__launch_bounds__(256, 3)
__global__ void k_attn(const unsigned short* __restrict__ qbuf,
                       const unsigned short* __restrict__ kbuf,
                       const unsigned short* __restrict__ vbuf,
                       const float* __restrict__ conf,
                       unsigned short* __restrict__ attbuf) {
  __shared__ unsigned short Kt[2][64 * 72];   // [kv][d], stride 72
  __shared__ unsigned short Vt[2][64 * 72];   // [d][kv], stride 72
  const int tid = threadIdx.x;
  const int lane = tid & 63, w = tid >> 6;
  const int l15 = lane & 15, g = lane >> 4;
  // XCD swizzle: grid 1568 = 8 XCDs x 196; each XCD owns 2 bh (K/V L2-resident)
  const int bid = blockIdx.x;
  const int xcd = bid & 7, idx = bid >> 3;    // idx 0..195
  const int sub = idx / 98;                   // 0..1
  const int xb = idx - sub * 98;
  const int bhid = xcd * 2 + sub;             // 0..15
  const int b = bhid >> 1, h = bhid & 1;
  const int bh = b * 2 + h;
  const int q0 = xb * 128 + 32 * w;           // this wave's 32 q rows

  const unsigned short* qsrc = qbuf + ((long)bh * NQTOK + q0) * 64;
  bf8 qf[2][2];
#pragma unroll
  for (int mr = 0; mr < 2; mr++)
#pragma unroll
    for (int ks = 0; ks < 2; ks++)
      qf[mr][ks] = *(const bf8*)(qsrc + (16 * mr + l15) * 64 + 32 * ks + (g << 3));

  const int srow = tid >> 2;
  const int scol = (tid & 3) << 4;
  const unsigned short* kg = kbuf + (long)bh * NSP * 64 + srow * 64 + scol;
  const unsigned short* vg = vbuf + (long)bh * 64 * NSP + (long)srow * NSP + scol;
  unsigned short* klds = &Kt[0][0] + srow * 72 + scol;
  unsigned short* vlds = &Vt[0][0] + srow * 72 + scol;

  uint4 kr0, kr1, vr0, vr1;
#define ISSUE(T)                                                   \
  do {                                                             \
    const unsigned short* kp_ = kg + (long)(T) * 4096;             \
    const unsigned short* vp_ = vg + (T) * 64;                     \
    kr0 = *(const uint4*)(kp_);                                    \
    kr1 = *(const uint4*)(kp_ + 8);                                \
    vr0 = *(const uint4*)(vp_);                                    \
    vr1 = *(const uint4*)(vp_ + 8);                                \
  } while (0)
#define STWRITE(BUF)                                               \
  do {                                                             \
    unsigned short* kd_ = klds + (BUF) * 4608;                     \
    unsigned short* vd_ = vlds + (BUF) * 4608;                     \
    *(uint4*)kd_ = kr0;  *(uint4*)(kd_ + 8) = kr1;                 \
    *(uint4*)vd_ = vr0;  *(uint4*)(vd_ + 8) = vr1;                 \
  } while (0)

  ISSUE(0);
  STWRITE(0);
  ISSUE(1);
  __syncthreads();

  const f4 fz = {0.f, 0.f, 0.f, 0.f};
  f4 ao[2][4], aol[2];
#pragma unroll
  for (int mr = 0; mr < 2; mr++) {
    aol[mr] = fz;
#pragma unroll
    for (int i = 0; i < 4; i++) ao[mr][i] = fz;
  }
  const short on = (short)0x3F80;                  // bf16 1.0
  const bf8 onesf = {on, on, on, on, on, on, on, on};
  const float* confb = conf + b * NSP;

#pragma unroll 2
  for (int t = 0; t < 13; t++) {
    const int cur = t & 1;
    const unsigned short* KtB = &Kt[cur][0];
    const unsigned short* VtB = &Vt[cur][0];
    bf8 kf[4][2];
#pragma unroll
    for (int mf = 0; mf < 4; mf++)
#pragma unroll
      for (int ks = 0; ks < 2; ks++)
        kf[mf][ks] = ldfrag(KtB, 72, 16 * mf, 32 * ks);
    bf8 vf[4][2];
#pragma unroll
    for (int nfd = 0; nfd < 4; nfd++)
#pragma unroll
      for (int ks = 0; ks < 2; ks++)
        vf[nfd][ks] = ldfrag(VtB, 72, 16 * nfd, 32 * ks);
    // conf as MFMA C-operand: C row = kv = 16mf+4g+reg, q-uniform across cols
    f4 cvi[4];
#pragma unroll
    for (int mf = 0; mf < 4; mf++) {
      float4 cv = *(const float4*)(confb + t * 64 + 16 * mf + 4 * g);
      cvi[mf][0] = cv.x; cvi[mf][1] = cv.y; cvi[mf][2] = cv.z; cvi[mf][3] = cv.w;
    }
#pragma unroll
    for (int mr = 0; mr < 2; mr++) {
      f4 s_[4];
#pragma unroll
      for (int mf = 0; mf < 4; mf++)
        s_[mf] = MFMA16(kf[mf][0], qf[mr][0], cvi[mf]);   // C-in = conf, no copy
#pragma unroll
      for (int mf = 0; mf < 4; mf++)
        s_[mf] = MFMA16(kf[mf][1], qf[mr][1], s_[mf]);
      unsigned W[4][2];
#pragma unroll
      for (int mf = 0; mf < 4; mf++) {
        float p0 = EXP2(s_[mf][0]);
        float p1 = EXP2(s_[mf][1]);
        float p2 = EXP2(s_[mf][2]);
        float p3 = EXP2(s_[mf][3]);
        W[mf][0] = pk2(p0, p1);
        W[mf][1] = pk2(p2, p3);
      }
#pragma unroll
      for (int ks = 0; ks < 2; ks++) {
        bf8 pa = rows2frag(W[2 * ks], W[2 * ks + 1]);
        aol[mr] = MFMA16(pa, onesf, aol[mr]);
#pragma unroll
        for (int nfd = 0; nfd < 4; nfd++)
          ao[mr][nfd] = MFMA16(pa, vf[nfd][ks], ao[mr][nfd]);
      }
    }
    if (t < 12) STWRITE(cur ^ 1);
    if (t < 11) ISSUE(t + 2);
    __syncthreads();
  }
#undef ISSUE
#undef STWRITE
#pragma unroll
  for (int mr = 0; mr < 2; mr++) {
    float inv[4];
#pragma unroll
    for (int reg = 0; reg < 4; reg++) inv[reg] = 1.0f / aol[mr][reg];
#pragma unroll
    for (int nfd = 0; nfd < 4; nfd++)
#pragma unroll
      for (int reg = 0; reg < 4; reg++) {
        int n = q0 + 16 * mr + 4 * g + reg;
        int col = h * 64 + 16 * nfd + l15;
        attbuf[((long)b * NQTOK + n) * 128 + col] = f2b(ao[mr][nfd][reg] * inv[reg]);
      }
  }
}

// ---------------- final projection (XCD-swizzled, B direct from pwt) ----------------
__launch_bounds__(256)
__global__ void k_proj(const unsigned short* __restrict__ attbuf,
                       const unsigned short* __restrict__ pwt,
                       const float* __restrict__ pb, float* __restrict__ out) {
  __shared__ unsigned short At[64 * 136];
  const int tid = threadIdx.x;
  const int lane = tid & 63, w = tid >> 6;
  const int l15 = lane & 15, g = lane >> 4;
  const int bid = blockIdx.x;
  const int r0 = (bid & 7) * NQTOK + (bid >> 3) * 64;   // batch (bid&7) on XCD (bid&7)
#pragma unroll
  for (int j = 0; j < 4; j++) {
    int id = tid + 256 * j;
    int row = id >> 4, c0 = (id & 15) << 3;
    *(uint4*)(At + row * 136 + c0) = *(const uint4*)(attbuf + (long)(r0 + row) * 128 + c0);
  }
  __syncthreads();
  const f4 fz = {0.f, 0.f, 0.f, 0.f};
  f4 acc[8];
#pragma unroll
  for (int i = 0; i < 8; i++) acc[i] = fz;
#pragma unroll
  for (int ks = 0; ks < 4; ks++) {
    bf8 a = ldfrag(At, 136, 16 * w, 32 * ks);
#pragma unroll
    for (int nf = 0; nf < 8; nf++) {
      bf8 bb = *(const bf8*)(pwt + (16 * nf + l15) * 128 + 32 * ks + (g << 3));
      acc[nf] = MFMA16(a, bb, acc[nf]);
    }
  }
#pragma unroll
  for (int nf = 0; nf < 8; nf++) {
    float bias = pb[16 * nf + l15];
#pragma unroll
    for (int reg = 0; reg < 4; reg++) {
      int r = r0 + 16 * w + 4 * g + reg;
      out[(long)r * 128 + 16 * nf + l15] = acc[nf][reg] + bias;
    }
  }
}

extern "C" void kernel_launch(void* const* d_in, const int* in_sizes, int n_in,
                              void* d_out, int out_size, void* d_ws, size_t ws_size,
                              hipStream_t stream) {
  const float* q_x  = (const float*)d_in[0];
  const float* kv_x = (const float*)d_in[1];
  const float* tsc  = (const float*)d_in[2];
  const int*   idxt = (const int*)d_in[3];
  const float* q_w  = (const float*)d_in[8];
  const float* kv_w = (const float*)d_in[9];
  const float* pw   = (const float*)d_in[10];
  const float* pb   = (const float*)d_in[11];
  const float* srw  = (const float*)d_in[12];
  const float* srb  = (const float*)d_in[13];
  const float* ng   = (const float*)d_in[14];
  const float* nb   = (const float*)d_in[15];
  float* outp = (float*)d_out;

  char* ws = (char*)d_ws;
  size_t off = 0;
  auto take = [&](size_t bytes) {
    char* p = ws + off;
    off += (bytes + 255) & ~(size_t)255;
    return p;
  };
  unsigned short* qwt   = (unsigned short*)take(128 * 128 * 2);
  unsigned short* pwt   = (unsigned short*)take(128 * 128 * 2);
  unsigned short* kvwt  = (unsigned short*)take(256 * 128 * 2);
  unsigned short* srwt  = (unsigned short*)take(128 * 2048 * 2);
  unsigned short* kvmap = (unsigned short*)take((size_t)NBATCH * 12544 * 128 * 2);
  float* conf_map       = (float*)take((size_t)NBATCH * 12544 * 4);
  unsigned short* kbuf  = (unsigned short*)take((size_t)NBATCH * 2 * NSP * 64 * 2);
  unsigned short* vbuf  = (unsigned short*)take((size_t)NBATCH * 2 * NSP * 64 * 2);
  float* conf           = (float*)take((size_t)NBATCH * NSP * 4);
  unsigned short* qbuf  = (unsigned short*)take((size_t)NBATCH * 2 * NQTOK * 64 * 2);
  unsigned short* attbuf = kvmap;  // kv_map dead after k_conv_ln_kv

  k_setup<<<256, 256, 0, stream>>>(q_w, kv_w, pw, srw, qwt, kvwt, pwt, srwt,
                                   (unsigned*)kbuf, (unsigned*)vbuf, conf);
  k_token2map<<<12544, 256, 0, stream>>>(kv_x, tsc, idxt, kvmap, conf_map);
  k_conv_ln_kv<<<98, 256, 0, stream>>>(kvmap, srwt, srb, ng, nb, kvwt, kbuf, vbuf,
                                       conf_map, conf);
  k_q<<<1568, 256, 0, stream>>>(q_x, qwt, qbuf);
  k_attn<<<1568, 256, 0, stream>>>(qbuf, kbuf, vbuf, conf, attbuf);
  k_proj<<<1568, 256, 0, stream>>>(attbuf, pwt, pb, outp);
}

// Round 14
// 202.668 us; speedup vs baseline: 1.2260x; 1.2206x over previous
//
#include <hip/hip_runtime.h>
#include <hip/hip_bf16.h>

// TCFormer dynamic attention, MI355X.
//  k_setup:      weights -> bf16 [n][k] transposes (qwt prescaled); k/v pad zero;
//                conf = -1e30.
//  k_token2map:  gather-average 4 tokens/cell -> kv_map bf16, conf_map f32.
//                XCD-swizzled (b=bid&7). LDS-FREE, standalone (R12 lesson).
//  k_conv_ln_kv: 4x4/s4 conv as MFMA GEMM with BOTH A and B LDS-staged (R13
//                lesson: B-direct from 512KB srwt at 98-block occupancy exposes
//                full load latency -> 8x slower; staging is mandatory here),
//                + fused LayerNorm -> LDS -> kv projection (B direct from 64KB
//                kvwt is fine) scatter to k [bh][ns][d], v [bh][d][ns]; + conf pool
//  k_q:          q_x @ qwt -> qbuf; A staged in LDS, B direct from 32KB qwt
//                (L1-hot + 1568-block TLP -> safe).
//  k_attn:       flash attn, 256 thr, 1 head/block, 128 q rows, K/V LDS
//                double-buffer, single barrier/tile, swapped QK^T, conf as direct
//                MFMA C-operand, v_exp_f32 softmax, l via ones-column MFMA,
//                XCD swizzle (each XCD owns 2 bh).
//  k_proj:       attbuf @ proj_w + proj_b -> f32 out; B direct from pwt.
//  REGISTER LESSON (R7+R10): launch_bounds 2nd arg is waves/EU. k_attn needs
//  ~84 VGPR + ~40 AGPR; 4 waves/EU caps the unified file at 128 -> spills.
//  (256,3) is its ceiling.
//  FUSION LESSON (R12): don't fuse resource-light latency-bound kernels into
//  resource-heavy ones - static LDS/VGPR tax kills the light kernel's occupancy.

#define NBATCH 8
#define NQTOK  12544
#define NSP    832
#define LOG2E  1.4426950408889634f
#define QSCALE (0.125f * LOG2E)

typedef __attribute__((ext_vector_type(8))) short bf8;
typedef __attribute__((ext_vector_type(4))) float f4;
typedef __attribute__((ext_vector_type(4))) unsigned short u16x4;
typedef __attribute__((ext_vector_type(2))) unsigned int u32x2;

#define MFMA16(a, b, c) __builtin_amdgcn_mfma_f32_16x16x32_bf16((a), (b), (c), 0, 0, 0)

#if __has_builtin(__builtin_amdgcn_exp2f)
#define EXP2(x) __builtin_amdgcn_exp2f(x)
#else
#define EXP2(x) exp2f(x)
#endif

__device__ __forceinline__ unsigned short f2b(float x) {
  union { float f; unsigned u; } v; v.f = x;
  unsigned r = v.u + 0x7FFFu + ((v.u >> 16) & 1u);
  return (unsigned short)(r >> 16);
}

__device__ __forceinline__ unsigned pk2(float lo, float hi) {
  float2 t; t.x = lo; t.y = hi;
  __hip_bfloat162 bb = __float22bfloat162_rn(t);
  union { __hip_bfloat162 b; unsigned u; } v; v.b = bb;
  return v.u;
}

// Row-layout reg pairs (rows 16mf+4g+reg, passthrough col l15) -> 8-wide-k frag.
__device__ __forceinline__ bf8 rows2frag(const unsigned W0[2], const unsigned W1[2]) {
  u32x2 r0 = __builtin_amdgcn_permlane32_swap(W0[0], W1[0], false, false);
  u32x2 t02 = __builtin_amdgcn_permlane16_swap(r0.x, r0.y, false, false);
  u32x2 r1 = __builtin_amdgcn_permlane32_swap(W0[1], W1[1], false, false);
  u32x2 t13 = __builtin_amdgcn_permlane16_swap(r1.x, r1.y, false, false);
  union { unsigned u[4]; bf8 v; } pa;
  pa.u[0] = t02.x; pa.u[1] = t13.x; pa.u[2] = t02.y; pa.u[3] = t13.y;
  return pa.v;
}

// lane holds tile[rbase + (lane&15)][kbase + 8*(lane>>4) .. +7]
__device__ __forceinline__ bf8 ldfrag(const unsigned short* t, int stride, int rbase, int kbase) {
  int lane = threadIdx.x & 63;
  return *(const bf8*)(t + (rbase + (lane & 15)) * stride + kbase + ((lane >> 4) << 3));
}

// ---------------- setup ----------------
__global__ void k_setup(const float* __restrict__ qw, const float* __restrict__ kvw,
                        const float* __restrict__ pw, const float* __restrict__ srw,
                        unsigned short* __restrict__ qwt, unsigned short* __restrict__ kvwt,
                        unsigned short* __restrict__ pwt, unsigned short* __restrict__ srwt,
                        unsigned* __restrict__ kb, unsigned* __restrict__ vb,
                        float* __restrict__ conf) {
  int tid = blockIdx.x * 256 + threadIdx.x;
  int nt = gridDim.x * 256;
  for (int i = tid; i < 128 * 128; i += nt) {
    int k = i >> 7, n = i & 127;
    qwt[n * 128 + k] = f2b(qw[k * 128 + n] * QSCALE);
    pwt[n * 128 + k] = f2b(pw[k * 128 + n]);
  }
  for (int i = tid; i < 128 * 256; i += nt) {
    int k = i >> 8, j = i & 255;
    kvwt[j * 128 + k] = f2b(kvw[k * 256 + j]);
  }
  for (int i = tid; i < 128 * 2048; i += nt) {
    int o = i >> 11, kk = i & 2047;
    int p = kk >> 7, c = kk & 127;
    srwt[o * 2048 + kk] = f2b(srw[o * 2048 + c * 16 + p]);
  }
  const int nu = NBATCH * 2 * NSP * 64 / 2;
  for (int i = tid; i < nu; i += nt) { kb[i] = 0u; vb[i] = 0u; }
  for (int i = tid; i < NBATCH * NSP; i += nt) conf[i] = -1e30f;
}

// ---------------- token2map (XCD-swizzled, LDS-free) ----------------
__global__ void k_token2map(const float* __restrict__ kv_x, const float* __restrict__ tsc,
                            const int* __restrict__ idxt,
                            unsigned short* __restrict__ kv_map, float* __restrict__ conf_map) {
  int tid = threadIdx.x;
  int bid = blockIdx.x;
  int b = bid & 7, pos = bid >> 3;                 // 1568 blocks/batch on one XCD
  int hw = pos * 8 + (tid >> 5);
  int cell = b * 12544 + hw;
  int c0 = (tid & 31) << 2;
  int h = hw / 112, w = hw - h * 112;
  const int* it = idxt + b * 50176;
  int t0 = it[(2 * h) * 224 + 2 * w];
  int t1 = it[(2 * h) * 224 + 2 * w + 1];
  int t2 = it[(2 * h + 1) * 224 + 2 * w];
  int t3 = it[(2 * h + 1) * 224 + 2 * w + 1];
  const float* base = kv_x + (long)b * 12544 * 128 + c0;
  const float recip = 1.0f / (4.0f + 1e-6f);
  float4 a0 = *(const float4*)(base + (long)t0 * 128);
  float4 a1 = *(const float4*)(base + (long)t1 * 128);
  float4 a2 = *(const float4*)(base + (long)t2 * 128);
  float4 a3 = *(const float4*)(base + (long)t3 * 128);
  u16x4 o;
  o[0] = f2b((a0.x + a1.x + a2.x + a3.x) * recip);
  o[1] = f2b((a0.y + a1.y + a2.y + a3.y) * recip);
  o[2] = f2b((a0.z + a1.z + a2.z + a3.z) * recip);
  o[3] = f2b((a0.w + a1.w + a2.w + a3.w) * recip);
  *(u16x4*)(kv_map + (long)cell * 128 + c0) = o;
  if ((tid & 31) == 0) {
    const float* ts = tsc + b * 12544;
    conf_map[cell] = (ts[t0] + ts[t1] + ts[t2] + ts[t3]) * recip;
  }
}

// ---------------- conv (patch GEMM, A+B staged) + LayerNorm + kv projection ----------------
__launch_bounds__(256)
__global__ void k_conv_ln_kv(const unsigned short* __restrict__ kv_map,
                             const unsigned short* __restrict__ srwt,
                             const float* __restrict__ srb, const float* __restrict__ ng,
                             const float* __restrict__ nb,
                             const unsigned short* __restrict__ kvwt,
                             unsigned short* __restrict__ kbuf,
                             unsigned short* __restrict__ vbuf,
                             const float* __restrict__ conf_map, float* __restrict__ conf) {
  __shared__ unsigned short At[64 * 136];
  __shared__ unsigned short Bt[128 * 136];
  const int tid = threadIdx.x;
  const int lane = tid & 63, w = tid >> 6;
  const int l15 = lane & 15, g = lane >> 4;
  const int r0 = blockIdx.x * 64;
  if (tid < 64) {
    int pos = r0 + tid;
    int bq = pos / 784, p2 = pos - bq * 784;
    int oh = p2 / 28, ow = p2 - oh * 28;
    float s = 0.f;
#pragma unroll
    for (int kh = 0; kh < 4; kh++)
#pragma unroll
      for (int kw = 0; kw < 4; kw++)
        s += conf_map[bq * 12544 + (4 * oh + kh) * 112 + 4 * ow + kw];
    conf[bq * NSP + p2] = s * (LOG2E / 16.0f);
  }
  const f4 fz = {0.f, 0.f, 0.f, 0.f};
  f4 acc[8];
#pragma unroll
  for (int i = 0; i < 8; i++) acc[i] = fz;

  for (int p = 0; p < 16; p++) {
#pragma unroll
    for (int j = 0; j < 4; j++) {
      int id = tid + 256 * j;
      int row = id >> 4, c0 = (id & 15) << 3;
      int rr = r0 + row;
      int bb = rr / 784, pos = rr - bb * 784;
      int oh = pos / 28, ow = pos - oh * 28;
      long src = ((long)(bb * 12544 + (4 * oh + (p >> 2)) * 112 + 4 * ow + (p & 3))) * 128 + c0;
      *(uint4*)(At + row * 136 + c0) = *(const uint4*)(kv_map + src);
    }
#pragma unroll
    for (int j = 0; j < 8; j++) {
      int id = tid + 256 * j;
      int row = id >> 4, c0 = (id & 15) << 3;
      *(uint4*)(Bt + row * 136 + c0) = *(const uint4*)(srwt + row * 2048 + p * 128 + c0);
    }
    __syncthreads();
#pragma unroll
    for (int ks = 0; ks < 4; ks++) {
      bf8 a = ldfrag(At, 136, 16 * w, 32 * ks);
#pragma unroll
      for (int nf = 0; nf < 8; nf++) {
        bf8 bb = ldfrag(Bt, 136, 16 * nf, 32 * ks);
        acc[nf] = MFMA16(a, bb, acc[nf]);
      }
    }
    __syncthreads();
  }
  float sum_[4] = {0.f, 0.f, 0.f, 0.f}, sq_[4] = {0.f, 0.f, 0.f, 0.f};
#pragma unroll
  for (int nf = 0; nf < 8; nf++) {
    float bias = srb[16 * nf + l15];
#pragma unroll
    for (int reg = 0; reg < 4; reg++) {
      float v = acc[nf][reg] + bias;
      acc[nf][reg] = v;
      sum_[reg] += v;
      sq_[reg] += v * v;
    }
  }
#pragma unroll
  for (int msk = 1; msk < 16; msk <<= 1)
#pragma unroll
    for (int reg = 0; reg < 4; reg++) {
      sum_[reg] += __shfl_xor(sum_[reg], msk, 64);
      sq_[reg] += __shfl_xor(sq_[reg], msk, 64);
    }
#pragma unroll
  for (int nf = 0; nf < 8; nf++) {
    float gc = ng[16 * nf + l15], bc = nb[16 * nf + l15];
#pragma unroll
    for (int reg = 0; reg < 4; reg++) {
      float mean = sum_[reg] * (1.0f / 128.0f);
      float var = sq_[reg] * (1.0f / 128.0f) - mean * mean;
      float v = (acc[nf][reg] - mean) * rsqrtf(var + 1e-5f) * gc + bc;
      At[(16 * w + 4 * g + reg) * 136 + 16 * nf + l15] = f2b(v);
    }
  }
  __syncthreads();
  f4 acc2[16];
#pragma unroll
  for (int i = 0; i < 16; i++) acc2[i] = fz;
#pragma unroll
  for (int ks = 0; ks < 4; ks++) {
    bf8 a = ldfrag(At, 136, 16 * w, 32 * ks);
#pragma unroll
    for (int nf = 0; nf < 16; nf++) {
      bf8 bb = *(const bf8*)(kvwt + (16 * nf + l15) * 128 + 32 * ks + (g << 3));
      acc2[nf] = MFMA16(a, bb, acc2[nf]);
    }
  }
#pragma unroll
  for (int nf = 0; nf < 16; nf++)
#pragma unroll
    for (int reg = 0; reg < 4; reg++) {
      int r = r0 + 16 * w + 4 * g + reg;
      int b = r / 784, ns = r - b * 784;
      int j = 16 * nf + l15;
      int sel = j >> 7, hh = (j >> 6) & 1, d = j & 63;
      unsigned short val = f2b(acc2[nf][reg]);
      if (sel == 0) kbuf[((long)(b * 2 + hh) * NSP + ns) * 64 + d] = val;
      else          vbuf[((long)(b * 2 + hh) * 64 + d) * NSP + ns] = val;
    }
}

// ---------------- q GEMM (XCD-swizzled, B direct from qwt) ----------------
__launch_bounds__(256)
__global__ void k_q(const float* __restrict__ q_x, const unsigned short* __restrict__ qwt,
                    unsigned short* __restrict__ qbuf) {
  __shared__ unsigned short At[64 * 136];
  const int tid = threadIdx.x;
  const int lane = tid & 63, w = tid >> 6;
  const int l15 = lane & 15, g = lane >> 4;
  const int bid = blockIdx.x;
  const int r0 = (bid & 7) * NQTOK + (bid >> 3) * 64;   // batch (bid&7) on XCD (bid&7)
#pragma unroll
  for (int j = 0; j < 8; j++) {
    int id = tid + 256 * j;
    int row = id >> 5, c0 = (id & 31) << 2;
    float4 v = *(const float4*)(q_x + (long)(r0 + row) * 128 + c0);
    u16x4 o;
    o[0] = f2b(v.x); o[1] = f2b(v.y); o[2] = f2b(v.z); o[3] = f2b(v.w);
    *(u16x4*)(At + row * 136 + c0) = o;
  }
  __syncthreads();
  const f4 fz = {0.f, 0.f, 0.f, 0.f};
  f4 acc[8];
#pragma unroll
  for (int i = 0; i < 8; i++) acc[i] = fz;
#pragma unroll
  for (int ks = 0; ks < 4; ks++) {
    bf8 a = ldfrag(At, 136, 16 * w, 32 * ks);
#pragma unroll
    for (int nf = 0; nf < 8; nf++) {
      bf8 bb = *(const bf8*)(qwt + (16 * nf + l15) * 128 + 32 * ks + (g << 3));
      acc[nf] = MFMA16(a, bb, acc[nf]);
    }
  }
#pragma unroll
  for (int nf = 0; nf < 8; nf++)
#pragma unroll
    for (int reg = 0; reg < 4; reg++) {
      int r = r0 + 16 * w + 4 * g + reg;
      int b = r / NQTOK, n = r - b * NQTOK;
      int j = 16 * nf + l15;
      int hh = j >> 6, d = j & 63;
      qbuf[((long)(b * 2 + hh) * NQTOK + n) * 64 + d] = f2b(acc[nf][reg]);
    }
}

// ---------------- flash attention (XCD swizzle, conf as direct C-operand) ----------------
__launch_bounds__(256, 3)
__global__ void k_attn(const unsigned short* __restrict__ qbuf,
                       const unsigned short* __restrict__ kbuf,
                       const unsigned short* __restrict__ vbuf,
                       const float* __restrict__ conf,
                       unsigned short* __restrict__ attbuf) {
  __shared__ unsigned short Kt[2][64 * 72];   // [kv][d], stride 72
  __shared__ unsigned short Vt[2][64 * 72];   // [d][kv], stride 72
  const int tid = threadIdx.x;
  const int lane = tid & 63, w = tid >> 6;
  const int l15 = lane & 15, g = lane >> 4;
  // XCD swizzle: grid 1568 = 8 XCDs x 196; each XCD owns 2 bh (K/V L2-resident)
  const int bid = blockIdx.x;
  const int xcd = bid & 7, idx = bid >> 3;    // idx 0..195
  const int sub = idx / 98;                   // 0..1
  const int xb = idx - sub * 98;
  const int bhid = xcd * 2 + sub;             // 0..15
  const int b = bhid >> 1, h = bhid & 1;
  const int bh = b * 2 + h;
  const int q0 = xb * 128 + 32 * w;           // this wave's 32 q rows

  const unsigned short* qsrc = qbuf + ((long)bh * NQTOK + q0) * 64;
  bf8 qf[2][2];
#pragma unroll
  for (int mr = 0; mr < 2; mr++)
#pragma unroll
    for (int ks = 0; ks < 2; ks++)
      qf[mr][ks] = *(const bf8*)(qsrc + (16 * mr + l15) * 64 + 32 * ks + (g << 3));

  const int srow = tid >> 2;
  const int scol = (tid & 3) << 4;
  const unsigned short* kg = kbuf + (long)bh * NSP * 64 + srow * 64 + scol;
  const unsigned short* vg = vbuf + (long)bh * 64 * NSP + (long)srow * NSP + scol;
  unsigned short* klds = &Kt[0][0] + srow * 72 + scol;
  unsigned short* vlds = &Vt[0][0] + srow * 72 + scol;

  uint4 kr0, kr1, vr0, vr1;
#define ISSUE(T)                                                   \
  do {                                                             \
    const unsigned short* kp_ = kg + (long)(T) * 4096;             \
    const unsigned short* vp_ = vg + (T) * 64;                     \
    kr0 = *(const uint4*)(kp_);                                    \
    kr1 = *(const uint4*)(kp_ + 8);                                \
    vr0 = *(const uint4*)(vp_);                                    \
    vr1 = *(const uint4*)(vp_ + 8);                                \
  } while (0)
#define STWRITE(BUF)                                               \
  do {                                                             \
    unsigned short* kd_ = klds + (BUF) * 4608;                     \
    unsigned short* vd_ = vlds + (BUF) * 4608;                     \
    *(uint4*)kd_ = kr0;  *(uint4*)(kd_ + 8) = kr1;                 \
    *(uint4*)vd_ = vr0;  *(uint4*)(vd_ + 8) = vr1;                 \
  } while (0)

  ISSUE(0);
  STWRITE(0);
  ISSUE(1);
  __syncthreads();

  const f4 fz = {0.f, 0.f, 0.f, 0.f};
  f4 ao[2][4], aol[2];
#pragma unroll
  for (int mr = 0; mr < 2; mr++) {
    aol[mr] = fz;
#pragma unroll
    for (int i = 0; i < 4; i++) ao[mr][i] = fz;
  }
  const short on = (short)0x3F80;                  // bf16 1.0
  const bf8 onesf = {on, on, on, on, on, on, on, on};
  const float* confb = conf + b * NSP;

#pragma unroll 2
  for (int t = 0; t < 13; t++) {
    const int cur = t & 1;
    const unsigned short* KtB = &Kt[cur][0];
    const unsigned short* VtB = &Vt[cur][0];
    bf8 kf[4][2];
#pragma unroll
    for (int mf = 0; mf < 4; mf++)
#pragma unroll
      for (int ks = 0; ks < 2; ks++)
        kf[mf][ks] = ldfrag(KtB, 72, 16 * mf, 32 * ks);
    bf8 vf[4][2];
#pragma unroll
    for (int nfd = 0; nfd < 4; nfd++)
#pragma unroll
      for (int ks = 0; ks < 2; ks++)
        vf[nfd][ks] = ldfrag(VtB, 72, 16 * nfd, 32 * ks);
    // conf as MFMA C-operand: C row = kv = 16mf+4g+reg, q-uniform across cols
    f4 cvi[4];
#pragma unroll
    for (int mf = 0; mf < 4; mf++) {
      float4 cv = *(const float4*)(confb + t * 64 + 16 * mf + 4 * g);
      cvi[mf][0] = cv.x; cvi[mf][1] = cv.y; cvi[mf][2] = cv.z; cvi[mf][3] = cv.w;
    }
#pragma unroll
    for (int mr = 0; mr < 2; mr++) {
      f4 s_[4];
#pragma unroll
      for (int mf = 0; mf < 4; mf++)
        s_[mf] = MFMA16(kf[mf][0], qf[mr][0], cvi[mf]);   // C-in = conf, no copy
#pragma unroll
      for (int mf = 0; mf < 4; mf++)
        s_[mf] = MFMA16(kf[mf][1], qf[mr][1], s_[mf]);
      unsigned W[4][2];
#pragma unroll
      for (int mf = 0; mf < 4; mf++) {
        float p0 = EXP2(s_[mf][0]);
        float p1 = EXP2(s_[mf][1]);
        float p2 = EXP2(s_[mf][2]);
        float p3 = EXP2(s_[mf][3]);
        W[mf][0] = pk2(p0, p1);
        W[mf][1] = pk2(p2, p3);
      }
#pragma unroll
      for (int ks = 0; ks < 2; ks++) {
        bf8 pa = rows2frag(W[2 * ks], W[2 * ks + 1]);
        aol[mr] = MFMA16(pa, onesf, aol[mr]);
#pragma unroll
        for (int nfd = 0; nfd < 4; nfd++)
          ao[mr][nfd] = MFMA16(pa, vf[nfd][ks], ao[mr][nfd]);
      }
    }
    if (t < 12) STWRITE(cur ^ 1);
    if (t < 11) ISSUE(t + 2);
    __syncthreads();
  }
#undef ISSUE
#undef STWRITE
#pragma unroll
  for (int mr = 0; mr < 2; mr++) {
    float inv[4];
#pragma unroll
    for (int reg = 0; reg < 4; reg++) inv[reg] = 1.0f / aol[mr][reg];
#pragma unroll
    for (int nfd = 0; nfd < 4; nfd++)
#pragma unroll
      for (int reg = 0; reg < 4; reg++) {
        int n = q0 + 16 * mr + 4 * g + reg;
        int col = h * 64 + 16 * nfd + l15;
        attbuf[((long)b * NQTOK + n) * 128 + col] = f2b(ao[mr][nfd][reg] * inv[reg]);
      }
  }
}

// ---------------- final projection (XCD-swizzled, B direct from pwt) ----------------
__launch_bounds__(256)
__global__ void k_proj(const unsigned short* __restrict__ attbuf,
                       const unsigned short* __restrict__ pwt,
                       const float* __restrict__ pb, float* __restrict__ out) {
  __shared__ unsigned short At[64 * 136];
  const int tid = threadIdx.x;
  const int lane = tid & 63, w = tid >> 6;
  const int l15 = lane & 15, g = lane >> 4;
  const int bid = blockIdx.x;
  const int r0 = (bid & 7) * NQTOK + (bid >> 3) * 64;   // batch (bid&7) on XCD (bid&7)
#pragma unroll
  for (int j = 0; j < 4; j++) {
    int id = tid + 256 * j;
    int row = id >> 4, c0 = (id & 15) << 3;
    *(uint4*)(At + row * 136 + c0) = *(const uint4*)(attbuf + (long)(r0 + row) * 128 + c0);
  }
  __syncthreads();
  const f4 fz = {0.f, 0.f, 0.f, 0.f};
  f4 acc[8];
#pragma unroll
  for (int i = 0; i < 8; i++) acc[i] = fz;
#pragma unroll
  for (int ks = 0; ks < 4; ks++) {
    bf8 a = ldfrag(At, 136, 16 * w, 32 * ks);
#pragma unroll
    for (int nf = 0; nf < 8; nf++) {
      bf8 bb = *(const bf8*)(pwt + (16 * nf + l15) * 128 + 32 * ks + (g << 3));
      acc[nf] = MFMA16(a, bb, acc[nf]);
    }
  }
#pragma unroll
  for (int nf = 0; nf < 8; nf++) {
    float bias = pb[16 * nf + l15];
#pragma unroll
    for (int reg = 0; reg < 4; reg++) {
      int r = r0 + 16 * w + 4 * g + reg;
      out[(long)r * 128 + 16 * nf + l15] = acc[nf][reg] + bias;
    }
  }
}

extern "C" void kernel_launch(void* const* d_in, const int* in_sizes, int n_in,
                              void* d_out, int out_size, void* d_ws, size_t ws_size,
                              hipStream_t stream) {
  const float* q_x  = (const float*)d_in[0];
  const float* kv_x = (const float*)d_in[1];
  const float* tsc  = (const float*)d_in[2];
  const int*   idxt = (const int*)d_in[3];
  const float* q_w  = (const float*)d_in[8];
  const float* kv_w = (const float*)d_in[9];
  const float* pw   = (const float*)d_in[10];
  const float* pb   = (const float*)d_in[11];
  const float* srw  = (const float*)d_in[12];
  const float* srb  = (const float*)d_in[13];
  const float* ng   = (const float*)d_in[14];
  const float* nb   = (const float*)d_in[15];
  float* outp = (float*)d_out;

  char* ws = (char*)d_ws;
  size_t off = 0;
  auto take = [&](size_t bytes) {
    char* p = ws + off;
    off += (bytes + 255) & ~(size_t)255;
    return p;
  };
  unsigned short* qwt   = (unsigned short*)take(128 * 128 * 2);
  unsigned short* pwt   = (unsigned short*)take(128 * 128 * 2);
  unsigned short* kvwt  = (unsigned short*)take(256 * 128 * 2);
  unsigned short* srwt  = (unsigned short*)take(128 * 2048 * 2);
  unsigned short* kvmap = (unsigned short*)take((size_t)NBATCH * 12544 * 128 * 2);
  float* conf_map       = (float*)take((size_t)NBATCH * 12544 * 4);
  unsigned short* kbuf  = (unsigned short*)take((size_t)NBATCH * 2 * NSP * 64 * 2);
  unsigned short* vbuf  = (unsigned short*)take((size_t)NBATCH * 2 * NSP * 64 * 2);
  float* conf           = (float*)take((size_t)NBATCH * NSP * 4);
  unsigned short* qbuf  = (unsigned short*)take((size_t)NBATCH * 2 * NQTOK * 64 * 2);
  unsigned short* attbuf = kvmap;  // kv_map dead after k_conv_ln_kv

  k_setup<<<256, 256, 0, stream>>>(q_w, kv_w, pw, srw, qwt, kvwt, pwt, srwt,
                                   (unsigned*)kbuf, (unsigned*)vbuf, conf);
  k_token2map<<<12544, 256, 0, stream>>>(kv_x, tsc, idxt, kvmap, conf_map);
  k_conv_ln_kv<<<98, 256, 0, stream>>>(kvmap, srwt, srb, ng, nb, kvwt, kbuf, vbuf,
                                       conf_map, conf);
  k_q<<<1568, 256, 0, stream>>>(q_x, qwt, qbuf);
  k_attn<<<1568, 256, 0, stream>>>(qbuf, kbuf, vbuf, conf, attbuf);
  k_proj<<<1568, 256, 0, stream>>>(attbuf, pwt, pb, outp);
}

// Round 15
// 159.528 us; speedup vs baseline: 1.5576x; 1.2704x over previous
//
#include <hip/hip_runtime.h>
#include <hip/hip_bf16.h>

// TCFormer dynamic attention, MI355X. Best-known configuration (R11 + conf-C).
//  k_token2map:  gather-average 4 tokens/cell -> kv_map bf16, conf_map f32.
//                XCD-swizzled (b = bid&7). Tail 256 blocks do weight setup.
//  k_conv_ln_kv: conv as MFMA GEMM, A+B LDS-staged (R13: B-direct from 512KB
//                srwt at 98 blocks = 8x slower) + LayerNorm -> LDS -> kv proj
//                (B direct from 64KB kvwt ok: 64 loads amortized); + conf pool
//  k_q:          q_x @ qwt -> qbuf, A+B LDS-staged (R14: per-MFMA global B-frag
//                loads are L1-BW-bound, ~2x slower), XCD-swizzled per batch
//  k_attn:       flash attn, 256 thr, 1 head/block, 128 q rows, K/V LDS
//                double-buffer, single barrier/tile, swapped QK^T, conf as
//                direct MFMA C-operand, v_exp_f32, l via ones-MFMA, XCD swizzle.
//  k_proj:       attbuf @ proj_w + proj_b -> f32 out, A+B staged, XCD-swizzled
//  REGISTER LESSON (R7+R10): launch_bounds arg2 is waves/EU; k_attn needs
//  ~84V+~40A regs -> (256,3) is its ceiling; requesting 4 spills ~600MB.
//  FUSION LESSON (R12): don't fuse LDS/VGPR-heavy work into latency-bound
//  light kernels. STAGING LESSON (R13/R14): MFMA B-operands must come from LDS.

#define NBATCH 8
#define NQTOK  12544
#define NSP    832
#define LOG2E  1.4426950408889634f
#define QSCALE (0.125f * LOG2E)

typedef __attribute__((ext_vector_type(8))) short bf8;
typedef __attribute__((ext_vector_type(4))) float f4;
typedef __attribute__((ext_vector_type(4))) unsigned short u16x4;
typedef __attribute__((ext_vector_type(2))) unsigned int u32x2;

#define MFMA16(a, b, c) __builtin_amdgcn_mfma_f32_16x16x32_bf16((a), (b), (c), 0, 0, 0)

#if __has_builtin(__builtin_amdgcn_exp2f)
#define EXP2(x) __builtin_amdgcn_exp2f(x)
#else
#define EXP2(x) exp2f(x)
#endif

__device__ __forceinline__ unsigned short f2b(float x) {
  union { float f; unsigned u; } v; v.f = x;
  unsigned r = v.u + 0x7FFFu + ((v.u >> 16) & 1u);
  return (unsigned short)(r >> 16);
}

__device__ __forceinline__ unsigned pk2(float lo, float hi) {
  float2 t; t.x = lo; t.y = hi;
  __hip_bfloat162 bb = __float22bfloat162_rn(t);
  union { __hip_bfloat162 b; unsigned u; } v; v.b = bb;
  return v.u;
}

// Row-layout reg pairs (rows 16mf+4g+reg, passthrough col l15) -> 8-wide-k frag.
__device__ __forceinline__ bf8 rows2frag(const unsigned W0[2], const unsigned W1[2]) {
  u32x2 r0 = __builtin_amdgcn_permlane32_swap(W0[0], W1[0], false, false);
  u32x2 t02 = __builtin_amdgcn_permlane16_swap(r0.x, r0.y, false, false);
  u32x2 r1 = __builtin_amdgcn_permlane32_swap(W0[1], W1[1], false, false);
  u32x2 t13 = __builtin_amdgcn_permlane16_swap(r1.x, r1.y, false, false);
  union { unsigned u[4]; bf8 v; } pa;
  pa.u[0] = t02.x; pa.u[1] = t13.x; pa.u[2] = t02.y; pa.u[3] = t13.y;
  return pa.v;
}

// lane holds tile[rbase + (lane&15)][kbase + 8*(lane>>4) .. +7]
__device__ __forceinline__ bf8 ldfrag(const unsigned short* t, int stride, int rbase, int kbase) {
  int lane = threadIdx.x & 63;
  return *(const bf8*)(t + (rbase + (lane & 15)) * stride + kbase + ((lane >> 4) << 3));
}

// ---------------- token2map (XCD-swizzled) + fused weight setup ----------------
__global__ void k_token2map(const float* __restrict__ kv_x, const float* __restrict__ tsc,
                            const int* __restrict__ idxt,
                            unsigned short* __restrict__ kv_map, float* __restrict__ conf_map,
                            const float* __restrict__ qw, const float* __restrict__ kvw,
                            const float* __restrict__ pw, const float* __restrict__ srw,
                            unsigned short* __restrict__ qwt, unsigned short* __restrict__ kvwt,
                            unsigned short* __restrict__ pwt, unsigned short* __restrict__ srwt,
                            unsigned* __restrict__ kb, unsigned* __restrict__ vb,
                            float* __restrict__ conf) {
  int tid = threadIdx.x;
  int bid = blockIdx.x;
  if (bid >= 12544) {                              // setup tail: 256 blocks
    int t = (bid - 12544) * 256 + tid;
    int nt = 256 * 256;
    for (int i = t; i < 128 * 128; i += nt) {
      int k = i >> 7, n = i & 127;
      qwt[n * 128 + k] = f2b(qw[k * 128 + n] * QSCALE);
      pwt[n * 128 + k] = f2b(pw[k * 128 + n]);
    }
    for (int i = t; i < 128 * 256; i += nt) {
      int k = i >> 8, j = i & 255;
      kvwt[j * 128 + k] = f2b(kvw[k * 256 + j]);
    }
    for (int i = t; i < 128 * 2048; i += nt) {
      int o = i >> 11, kk = i & 2047;
      int p = kk >> 7, c = kk & 127;
      srwt[o * 2048 + kk] = f2b(srw[o * 2048 + c * 16 + p]);
    }
    const int nu = NBATCH * 2 * NSP * 64 / 2;
    for (int i = t; i < nu; i += nt) { kb[i] = 0u; vb[i] = 0u; }
    for (int i = t; i < NBATCH * NSP; i += nt) conf[i] = -1e30f;
    return;
  }
  int b = bid & 7, pos = bid >> 3;                 // 1568 blocks/batch on one XCD
  int hw = pos * 8 + (tid >> 5);
  int cell = b * 12544 + hw;
  int c0 = (tid & 31) << 2;
  int h = hw / 112, w = hw - h * 112;
  const int* it = idxt + b * 50176;
  int t0 = it[(2 * h) * 224 + 2 * w];
  int t1 = it[(2 * h) * 224 + 2 * w + 1];
  int t2 = it[(2 * h + 1) * 224 + 2 * w];
  int t3 = it[(2 * h + 1) * 224 + 2 * w + 1];
  const float* base = kv_x + (long)b * 12544 * 128 + c0;
  const float recip = 1.0f / (4.0f + 1e-6f);
  float4 a0 = *(const float4*)(base + (long)t0 * 128);
  float4 a1 = *(const float4*)(base + (long)t1 * 128);
  float4 a2 = *(const float4*)(base + (long)t2 * 128);
  float4 a3 = *(const float4*)(base + (long)t3 * 128);
  u16x4 o;
  o[0] = f2b((a0.x + a1.x + a2.x + a3.x) * recip);
  o[1] = f2b((a0.y + a1.y + a2.y + a3.y) * recip);
  o[2] = f2b((a0.z + a1.z + a2.z + a3.z) * recip);
  o[3] = f2b((a0.w + a1.w + a2.w + a3.w) * recip);
  *(u16x4*)(kv_map + (long)cell * 128 + c0) = o;
  if ((tid & 31) == 0) {
    const float* ts = tsc + b * 12544;
    conf_map[cell] = (ts[t0] + ts[t1] + ts[t2] + ts[t3]) * recip;
  }
}

// ---------------- conv (patch GEMM, A+B staged) + LayerNorm + kv projection ----------------
__launch_bounds__(256)
__global__ void k_conv_ln_kv(const unsigned short* __restrict__ kv_map,
                             const unsigned short* __restrict__ srwt,
                             const float* __restrict__ srb, const float* __restrict__ ng,
                             const float* __restrict__ nb,
                             const unsigned short* __restrict__ kvwt,
                             unsigned short* __restrict__ kbuf,
                             unsigned short* __restrict__ vbuf,
                             const float* __restrict__ conf_map, float* __restrict__ conf) {
  __shared__ unsigned short At[64 * 136];
  __shared__ unsigned short Bt[128 * 136];
  const int tid = threadIdx.x;
  const int lane = tid & 63, w = tid >> 6;
  const int l15 = lane & 15, g = lane >> 4;
  const int r0 = blockIdx.x * 64;
  if (tid < 64) {
    int pos = r0 + tid;
    int bq = pos / 784, p2 = pos - bq * 784;
    int oh = p2 / 28, ow = p2 - oh * 28;
    float s = 0.f;
#pragma unroll
    for (int kh = 0; kh < 4; kh++)
#pragma unroll
      for (int kw = 0; kw < 4; kw++)
        s += conf_map[bq * 12544 + (4 * oh + kh) * 112 + 4 * ow + kw];
    conf[bq * NSP + p2] = s * (LOG2E / 16.0f);
  }
  const f4 fz = {0.f, 0.f, 0.f, 0.f};
  f4 acc[8];
#pragma unroll
  for (int i = 0; i < 8; i++) acc[i] = fz;

  for (int p = 0; p < 16; p++) {
#pragma unroll
    for (int j = 0; j < 4; j++) {
      int id = tid + 256 * j;
      int row = id >> 4, c0 = (id & 15) << 3;
      int rr = r0 + row;
      int bb = rr / 784, pos = rr - bb * 784;
      int oh = pos / 28, ow = pos - oh * 28;
      long src = ((long)(bb * 12544 + (4 * oh + (p >> 2)) * 112 + 4 * ow + (p & 3))) * 128 + c0;
      *(uint4*)(At + row * 136 + c0) = *(const uint4*)(kv_map + src);
    }
#pragma unroll
    for (int j = 0; j < 8; j++) {
      int id = tid + 256 * j;
      int row = id >> 4, c0 = (id & 15) << 3;
      *(uint4*)(Bt + row * 136 + c0) = *(const uint4*)(srwt + row * 2048 + p * 128 + c0);
    }
    __syncthreads();
#pragma unroll
    for (int ks = 0; ks < 4; ks++) {
      bf8 a = ldfrag(At, 136, 16 * w, 32 * ks);
#pragma unroll
      for (int nf = 0; nf < 8; nf++) {
        bf8 bb = ldfrag(Bt, 136, 16 * nf, 32 * ks);
        acc[nf] = MFMA16(a, bb, acc[nf]);
      }
    }
    __syncthreads();
  }
  float sum_[4] = {0.f, 0.f, 0.f, 0.f}, sq_[4] = {0.f, 0.f, 0.f, 0.f};
#pragma unroll
  for (int nf = 0; nf < 8; nf++) {
    float bias = srb[16 * nf + l15];
#pragma unroll
    for (int reg = 0; reg < 4; reg++) {
      float v = acc[nf][reg] + bias;
      acc[nf][reg] = v;
      sum_[reg] += v;
      sq_[reg] += v * v;
    }
  }
#pragma unroll
  for (int msk = 1; msk < 16; msk <<= 1)
#pragma unroll
    for (int reg = 0; reg < 4; reg++) {
      sum_[reg] += __shfl_xor(sum_[reg], msk, 64);
      sq_[reg] += __shfl_xor(sq_[reg], msk, 64);
    }
#pragma unroll
  for (int nf = 0; nf < 8; nf++) {
    float gc = ng[16 * nf + l15], bc = nb[16 * nf + l15];
#pragma unroll
    for (int reg = 0; reg < 4; reg++) {
      float mean = sum_[reg] * (1.0f / 128.0f);
      float var = sq_[reg] * (1.0f / 128.0f) - mean * mean;
      float v = (acc[nf][reg] - mean) * rsqrtf(var + 1e-5f) * gc + bc;
      At[(16 * w + 4 * g + reg) * 136 + 16 * nf + l15] = f2b(v);
    }
  }
  __syncthreads();
  f4 acc2[16];
#pragma unroll
  for (int i = 0; i < 16; i++) acc2[i] = fz;
#pragma unroll
  for (int ks = 0; ks < 4; ks++) {
    bf8 a = ldfrag(At, 136, 16 * w, 32 * ks);
#pragma unroll
    for (int nf = 0; nf < 16; nf++) {
      bf8 bb = *(const bf8*)(kvwt + (16 * nf + l15) * 128 + 32 * ks + (g << 3));
      acc2[nf] = MFMA16(a, bb, acc2[nf]);
    }
  }
#pragma unroll
  for (int nf = 0; nf < 16; nf++)
#pragma unroll
    for (int reg = 0; reg < 4; reg++) {
      int r = r0 + 16 * w + 4 * g + reg;
      int b = r / 784, ns = r - b * 784;
      int j = 16 * nf + l15;
      int sel = j >> 7, hh = (j >> 6) & 1, d = j & 63;
      unsigned short val = f2b(acc2[nf][reg]);
      if (sel == 0) kbuf[((long)(b * 2 + hh) * NSP + ns) * 64 + d] = val;
      else          vbuf[((long)(b * 2 + hh) * 64 + d) * NSP + ns] = val;
    }
}

// ---------------- q GEMM (A+B staged, XCD-swizzled per batch) ----------------
__launch_bounds__(256)
__global__ void k_q(const float* __restrict__ q_x, const unsigned short* __restrict__ qwt,
                    unsigned short* __restrict__ qbuf) {
  __shared__ unsigned short At[64 * 136];
  __shared__ unsigned short Bt[128 * 136];
  const int tid = threadIdx.x;
  const int lane = tid & 63, w = tid >> 6;
  const int l15 = lane & 15, g = lane >> 4;
  const int bid = blockIdx.x;
  const int r0 = (bid & 7) * NQTOK + (bid >> 3) * 64;   // batch (bid&7) on XCD (bid&7)
#pragma unroll
  for (int j = 0; j < 8; j++) {
    int id = tid + 256 * j;
    int row = id >> 5, c0 = (id & 31) << 2;
    float4 v = *(const float4*)(q_x + (long)(r0 + row) * 128 + c0);
    u16x4 o;
    o[0] = f2b(v.x); o[1] = f2b(v.y); o[2] = f2b(v.z); o[3] = f2b(v.w);
    *(u16x4*)(At + row * 136 + c0) = o;
  }
#pragma unroll
  for (int j = 0; j < 8; j++) {
    int id = tid + 256 * j;
    int row = id >> 4, c0 = (id & 15) << 3;
    *(uint4*)(Bt + row * 136 + c0) = *(const uint4*)(qwt + (long)row * 128 + c0);
  }
  __syncthreads();
  const f4 fz = {0.f, 0.f, 0.f, 0.f};
  f4 acc[8];
#pragma unroll
  for (int i = 0; i < 8; i++) acc[i] = fz;
#pragma unroll
  for (int ks = 0; ks < 4; ks++) {
    bf8 a = ldfrag(At, 136, 16 * w, 32 * ks);
#pragma unroll
    for (int nf = 0; nf < 8; nf++) {
      bf8 bb = ldfrag(Bt, 136, 16 * nf, 32 * ks);
      acc[nf] = MFMA16(a, bb, acc[nf]);
    }
  }
#pragma unroll
  for (int nf = 0; nf < 8; nf++)
#pragma unroll
    for (int reg = 0; reg < 4; reg++) {
      int r = r0 + 16 * w + 4 * g + reg;
      int b = r / NQTOK, n = r - b * NQTOK;
      int j = 16 * nf + l15;
      int hh = j >> 6, d = j & 63;
      qbuf[((long)(b * 2 + hh) * NQTOK + n) * 64 + d] = f2b(acc[nf][reg]);
    }
}

// ---------------- flash attention (XCD swizzle, conf as direct C-operand) ----------------
__launch_bounds__(256, 3)
__global__ void k_attn(const unsigned short* __restrict__ qbuf,
                       const unsigned short* __restrict__ kbuf,
                       const unsigned short* __restrict__ vbuf,
                       const float* __restrict__ conf,
                       unsigned short* __restrict__ attbuf) {
  __shared__ unsigned short Kt[2][64 * 72];   // [kv][d], stride 72
  __shared__ unsigned short Vt[2][64 * 72];   // [d][kv], stride 72
  const int tid = threadIdx.x;
  const int lane = tid & 63, w = tid >> 6;
  const int l15 = lane & 15, g = lane >> 4;
  // XCD swizzle: grid 1568 = 8 XCDs x 196; each XCD owns 2 bh (K/V L2-resident)
  const int bid = blockIdx.x;
  const int xcd = bid & 7, idx = bid >> 3;    // idx 0..195
  const int sub = idx / 98;                   // 0..1
  const int xb = idx - sub * 98;
  const int bhid = xcd * 2 + sub;             // 0..15
  const int b = bhid >> 1, h = bhid & 1;
  const int bh = b * 2 + h;
  const int q0 = xb * 128 + 32 * w;           // this wave's 32 q rows

  const unsigned short* qsrc = qbuf + ((long)bh * NQTOK + q0) * 64;
  bf8 qf[2][2];
#pragma unroll
  for (int mr = 0; mr < 2; mr++)
#pragma unroll
    for (int ks = 0; ks < 2; ks++)
      qf[mr][ks] = *(const bf8*)(qsrc + (16 * mr + l15) * 64 + 32 * ks + (g << 3));

  const int srow = tid >> 2;
  const int scol = (tid & 3) << 4;
  const unsigned short* kg = kbuf + (long)bh * NSP * 64 + srow * 64 + scol;
  const unsigned short* vg = vbuf + (long)bh * 64 * NSP + (long)srow * NSP + scol;
  unsigned short* klds = &Kt[0][0] + srow * 72 + scol;
  unsigned short* vlds = &Vt[0][0] + srow * 72 + scol;

  uint4 kr0, kr1, vr0, vr1;
#define ISSUE(T)                                                   \
  do {                                                             \
    const unsigned short* kp_ = kg + (long)(T) * 4096;             \
    const unsigned short* vp_ = vg + (T) * 64;                     \
    kr0 = *(const uint4*)(kp_);                                    \
    kr1 = *(const uint4*)(kp_ + 8);                                \
    vr0 = *(const uint4*)(vp_);                                    \
    vr1 = *(const uint4*)(vp_ + 8);                                \
  } while (0)
#define STWRITE(BUF)                                               \
  do {                                                             \
    unsigned short* kd_ = klds + (BUF) * 4608;                     \
    unsigned short* vd_ = vlds + (BUF) * 4608;                     \
    *(uint4*)kd_ = kr0;  *(uint4*)(kd_ + 8) = kr1;                 \
    *(uint4*)vd_ = vr0;  *(uint4*)(vd_ + 8) = vr1;                 \
  } while (0)

  ISSUE(0);
  STWRITE(0);
  ISSUE(1);
  __syncthreads();

  const f4 fz = {0.f, 0.f, 0.f, 0.f};
  f4 ao[2][4], aol[2];
#pragma unroll
  for (int mr = 0; mr < 2; mr++) {
    aol[mr] = fz;
#pragma unroll
    for (int i = 0; i < 4; i++) ao[mr][i] = fz;
  }
  const short on = (short)0x3F80;                  // bf16 1.0
  const bf8 onesf = {on, on, on, on, on, on, on, on};
  const float* confb = conf + b * NSP;

#pragma unroll 2
  for (int t = 0; t < 13; t++) {
    const int cur = t & 1;
    const unsigned short* KtB = &Kt[cur][0];
    const unsigned short* VtB = &Vt[cur][0];
    bf8 kf[4][2];
#pragma unroll
    for (int mf = 0; mf < 4; mf++)
#pragma unroll
      for (int ks = 0; ks < 2; ks++)
        kf[mf][ks] = ldfrag(KtB, 72, 16 * mf, 32 * ks);
    bf8 vf[4][2];
#pragma unroll
    for (int nfd = 0; nfd < 4; nfd++)
#pragma unroll
      for (int ks = 0; ks < 2; ks++)
        vf[nfd][ks] = ldfrag(VtB, 72, 16 * nfd, 32 * ks);
    // conf as MFMA C-operand: C row = kv = 16mf+4g+reg, q-uniform across cols
    f4 cvi[4];
#pragma unroll
    for (int mf = 0; mf < 4; mf++) {
      float4 cv = *(const float4*)(confb + t * 64 + 16 * mf + 4 * g);
      cvi[mf][0] = cv.x; cvi[mf][1] = cv.y; cvi[mf][2] = cv.z; cvi[mf][3] = cv.w;
    }
#pragma unroll
    for (int mr = 0; mr < 2; mr++) {
      f4 s_[4];
#pragma unroll
      for (int mf = 0; mf < 4; mf++)
        s_[mf] = MFMA16(kf[mf][0], qf[mr][0], cvi[mf]);   // C-in = conf, no copy
#pragma unroll
      for (int mf = 0; mf < 4; mf++)
        s_[mf] = MFMA16(kf[mf][1], qf[mr][1], s_[mf]);
      unsigned W[4][2];
#pragma unroll
      for (int mf = 0; mf < 4; mf++) {
        float p0 = EXP2(s_[mf][0]);
        float p1 = EXP2(s_[mf][1]);
        float p2 = EXP2(s_[mf][2]);
        float p3 = EXP2(s_[mf][3]);
        W[mf][0] = pk2(p0, p1);
        W[mf][1] = pk2(p2, p3);
      }
#pragma unroll
      for (int ks = 0; ks < 2; ks++) {
        bf8 pa = rows2frag(W[2 * ks], W[2 * ks + 1]);
        aol[mr] = MFMA16(pa, onesf, aol[mr]);
#pragma unroll
        for (int nfd = 0; nfd < 4; nfd++)
          ao[mr][nfd] = MFMA16(pa, vf[nfd][ks], ao[mr][nfd]);
      }
    }
    if (t < 12) STWRITE(cur ^ 1);
    if (t < 11) ISSUE(t + 2);
    __syncthreads();
  }
#undef ISSUE
#undef STWRITE
#pragma unroll
  for (int mr = 0; mr < 2; mr++) {
    float inv[4];
#pragma unroll
    for (int reg = 0; reg < 4; reg++) inv[reg] = 1.0f / aol[mr][reg];
#pragma unroll
    for (int nfd = 0; nfd < 4; nfd++)
#pragma unroll
      for (int reg = 0; reg < 4; reg++) {
        int n = q0 + 16 * mr + 4 * g + reg;
        int col = h * 64 + 16 * nfd + l15;
        attbuf[((long)b * NQTOK + n) * 128 + col] = f2b(ao[mr][nfd][reg] * inv[reg]);
      }
  }
}

// ---------------- final projection (A+B staged, XCD-swizzled per batch) ----------------
__launch_bounds__(256)
__global__ void k_proj(const unsigned short* __restrict__ attbuf,
                       const unsigned short* __restrict__ pwt,
                       const float* __restrict__ pb, float* __restrict__ out) {
  __shared__ unsigned short At[64 * 136];
  __shared__ unsigned short Bt[128 * 136];
  const int tid = threadIdx.x;
  const int lane = tid & 63, w = tid >> 6;
  const int l15 = lane & 15, g = lane >> 4;
  const int bid = blockIdx.x;
  const int r0 = (bid & 7) * NQTOK + (bid >> 3) * 64;   // batch (bid&7) on XCD (bid&7)
#pragma unroll
  for (int j = 0; j < 4; j++) {
    int id = tid + 256 * j;
    int row = id >> 4, c0 = (id & 15) << 3;
    *(uint4*)(At + row * 136 + c0) = *(const uint4*)(attbuf + (long)(r0 + row) * 128 + c0);
  }
#pragma unroll
  for (int j = 0; j < 8; j++) {
    int id = tid + 256 * j;
    int row = id >> 4, c0 = (id & 15) << 3;
    *(uint4*)(Bt + row * 136 + c0) = *(const uint4*)(pwt + (long)row * 128 + c0);
  }
  __syncthreads();
  const f4 fz = {0.f, 0.f, 0.f, 0.f};
  f4 acc[8];
#pragma unroll
  for (int i = 0; i < 8; i++) acc[i] = fz;
#pragma unroll
  for (int ks = 0; ks < 4; ks++) {
    bf8 a = ldfrag(At, 136, 16 * w, 32 * ks);
#pragma unroll
    for (int nf = 0; nf < 8; nf++) {
      bf8 bb = ldfrag(Bt, 136, 16 * nf, 32 * ks);
      acc[nf] = MFMA16(a, bb, acc[nf]);
    }
  }
#pragma unroll
  for (int nf = 0; nf < 8; nf++) {
    float bias = pb[16 * nf + l15];
#pragma unroll
    for (int reg = 0; reg < 4; reg++) {
      int r = r0 + 16 * w + 4 * g + reg;
      out[(long)r * 128 + 16 * nf + l15] = acc[nf][reg] + bias;
    }
  }
}

extern "C" void kernel_launch(void* const* d_in, const int* in_sizes, int n_in,
                              void* d_out, int out_size, void* d_ws, size_t ws_size,
                              hipStream_t stream) {
  const float* q_x  = (const float*)d_in[0];
  const float* kv_x = (const float*)d_in[1];
  const float* tsc  = (const float*)d_in[2];
  const int*   idxt = (const int*)d_in[3];
  const float* q_w  = (const float*)d_in[8];
  const float* kv_w = (const float*)d_in[9];
  const float* pw   = (const float*)d_in[10];
  const float* pb   = (const float*)d_in[11];
  const float* srw  = (const float*)d_in[12];
  const float* srb  = (const float*)d_in[13];
  const float* ng   = (const float*)d_in[14];
  const float* nb   = (const float*)d_in[15];
  float* outp = (float*)d_out;

  char* ws = (char*)d_ws;
  size_t off = 0;
  auto take = [&](size_t bytes) {
    char* p = ws + off;
    off += (bytes + 255) & ~(size_t)255;
    return p;
  };
  unsigned short* qwt   = (unsigned short*)take(128 * 128 * 2);
  unsigned short* pwt   = (unsigned short*)take(128 * 128 * 2);
  unsigned short* kvwt  = (unsigned short*)take(256 * 128 * 2);
  unsigned short* srwt  = (unsigned short*)take(128 * 2048 * 2);
  unsigned short* kvmap = (unsigned short*)take((size_t)NBATCH * 12544 * 128 * 2);
  float* conf_map       = (float*)take((size_t)NBATCH * 12544 * 4);
  unsigned short* kbuf  = (unsigned short*)take((size_t)NBATCH * 2 * NSP * 64 * 2);
  unsigned short* vbuf  = (unsigned short*)take((size_t)NBATCH * 2 * NSP * 64 * 2);
  float* conf           = (float*)take((size_t)NBATCH * NSP * 4);
  unsigned short* qbuf  = (unsigned short*)take((size_t)NBATCH * 2 * NQTOK * 64 * 2);
  unsigned short* attbuf = kvmap;  // kv_map dead after k_conv_ln_kv

  k_token2map<<<12800, 256, 0, stream>>>(kv_x, tsc, idxt, kvmap, conf_map,
                                         q_w, kv_w, pw, srw, qwt, kvwt, pwt, srwt,
                                         (unsigned*)kbuf, (unsigned*)vbuf, conf);
  k_conv_ln_kv<<<98, 256, 0, stream>>>(kvmap, srwt, srb, ng, nb, kvwt, kbuf, vbuf,
                                       conf_map, conf);
  k_q<<<1568, 256, 0, stream>>>(q_x, qwt, qbuf);
  k_attn<<<1568, 256, 0, stream>>>(qbuf, kbuf, vbuf, conf, attbuf);
  k_proj<<<1568, 256, 0, stream>>>(attbuf, pwt, pb, outp);
}

// Round 16
// 152.333 us; speedup vs baseline: 1.6312x; 1.0472x over previous
//
#include <hip/hip_runtime.h>
#include <hip/hip_bf16.h>

// TCFormer dynamic attention, MI355X. R15 config + k_attn register diet.
//  k_token2map:  gather-average 4 tokens/cell -> kv_map bf16, conf_map f32.
//                XCD-swizzled (b = bid&7). Tail 256 blocks do weight setup.
//  k_conv_ln_kv: conv as MFMA GEMM, A+B LDS-staged + LayerNorm -> LDS -> kv proj
//                (B direct from 64KB kvwt ok); + conf pool
//  k_q:          q_x @ qwt -> qbuf, A+B LDS-staged, XCD-swizzled per batch
//  k_attn:       flash attn, 256 thr, 1 head/block, 128 q rows, K/V LDS
//                double-buffer, single barrier/tile, swapped QK^T, conf as
//                direct MFMA C-operand, v_exp_f32, l via ones-MFMA, XCD swizzle.
//                V-frags loaded JUST-IN-TIME in PV loop (drops resident vf[4][2]
//                = 32 VGPRs; R15 showed 2 waves/SIMD register-limited at ~170+
//                combined regs -> diet targets 3 waves/SIMD).
//  k_proj:       attbuf @ proj_w + proj_b -> f32 out, A+B staged, XCD-swizzled
//  REGISTER LESSON (R7+R10): launch_bounds arg2 is waves/EU; over-requesting
//  spills ~600MB scratch. FUSION LESSON (R12): don't fuse LDS-heavy work into
//  latency-bound kernels. STAGING LESSON (R13/R14): MFMA B-operands from LDS.

#define NBATCH 8
#define NQTOK  12544
#define NSP    832
#define LOG2E  1.4426950408889634f
#define QSCALE (0.125f * LOG2E)

typedef __attribute__((ext_vector_type(8))) short bf8;
typedef __attribute__((ext_vector_type(4))) float f4;
typedef __attribute__((ext_vector_type(4))) unsigned short u16x4;
typedef __attribute__((ext_vector_type(2))) unsigned int u32x2;

#define MFMA16(a, b, c) __builtin_amdgcn_mfma_f32_16x16x32_bf16((a), (b), (c), 0, 0, 0)

#if __has_builtin(__builtin_amdgcn_exp2f)
#define EXP2(x) __builtin_amdgcn_exp2f(x)
#else
#define EXP2(x) exp2f(x)
#endif

__device__ __forceinline__ unsigned short f2b(float x) {
  union { float f; unsigned u; } v; v.f = x;
  unsigned r = v.u + 0x7FFFu + ((v.u >> 16) & 1u);
  return (unsigned short)(r >> 16);
}

__device__ __forceinline__ unsigned pk2(float lo, float hi) {
  float2 t; t.x = lo; t.y = hi;
  __hip_bfloat162 bb = __float22bfloat162_rn(t);
  union { __hip_bfloat162 b; unsigned u; } v; v.b = bb;
  return v.u;
}

// Row-layout reg pairs (rows 16mf+4g+reg, passthrough col l15) -> 8-wide-k frag.
__device__ __forceinline__ bf8 rows2frag(const unsigned W0[2], const unsigned W1[2]) {
  u32x2 r0 = __builtin_amdgcn_permlane32_swap(W0[0], W1[0], false, false);
  u32x2 t02 = __builtin_amdgcn_permlane16_swap(r0.x, r0.y, false, false);
  u32x2 r1 = __builtin_amdgcn_permlane32_swap(W0[1], W1[1], false, false);
  u32x2 t13 = __builtin_amdgcn_permlane16_swap(r1.x, r1.y, false, false);
  union { unsigned u[4]; bf8 v; } pa;
  pa.u[0] = t02.x; pa.u[1] = t13.x; pa.u[2] = t02.y; pa.u[3] = t13.y;
  return pa.v;
}

// lane holds tile[rbase + (lane&15)][kbase + 8*(lane>>4) .. +7]
__device__ __forceinline__ bf8 ldfrag(const unsigned short* t, int stride, int rbase, int kbase) {
  int lane = threadIdx.x & 63;
  return *(const bf8*)(t + (rbase + (lane & 15)) * stride + kbase + ((lane >> 4) << 3));
}

// ---------------- token2map (XCD-swizzled) + fused weight setup ----------------
__global__ void k_token2map(const float* __restrict__ kv_x, const float* __restrict__ tsc,
                            const int* __restrict__ idxt,
                            unsigned short* __restrict__ kv_map, float* __restrict__ conf_map,
                            const float* __restrict__ qw, const float* __restrict__ kvw,
                            const float* __restrict__ pw, const float* __restrict__ srw,
                            unsigned short* __restrict__ qwt, unsigned short* __restrict__ kvwt,
                            unsigned short* __restrict__ pwt, unsigned short* __restrict__ srwt,
                            unsigned* __restrict__ kb, unsigned* __restrict__ vb,
                            float* __restrict__ conf) {
  int tid = threadIdx.x;
  int bid = blockIdx.x;
  if (bid >= 12544) {                              // setup tail: 256 blocks
    int t = (bid - 12544) * 256 + tid;
    int nt = 256 * 256;
    for (int i = t; i < 128 * 128; i += nt) {
      int k = i >> 7, n = i & 127;
      qwt[n * 128 + k] = f2b(qw[k * 128 + n] * QSCALE);
      pwt[n * 128 + k] = f2b(pw[k * 128 + n]);
    }
    for (int i = t; i < 128 * 256; i += nt) {
      int k = i >> 8, j = i & 255;
      kvwt[j * 128 + k] = f2b(kvw[k * 256 + j]);
    }
    for (int i = t; i < 128 * 2048; i += nt) {
      int o = i >> 11, kk = i & 2047;
      int p = kk >> 7, c = kk & 127;
      srwt[o * 2048 + kk] = f2b(srw[o * 2048 + c * 16 + p]);
    }
    const int nu = NBATCH * 2 * NSP * 64 / 2;
    for (int i = t; i < nu; i += nt) { kb[i] = 0u; vb[i] = 0u; }
    for (int i = t; i < NBATCH * NSP; i += nt) conf[i] = -1e30f;
    return;
  }
  int b = bid & 7, pos = bid >> 3;                 // 1568 blocks/batch on one XCD
  int hw = pos * 8 + (tid >> 5);
  int cell = b * 12544 + hw;
  int c0 = (tid & 31) << 2;
  int h = hw / 112, w = hw - h * 112;
  const int* it = idxt + b * 50176;
  int t0 = it[(2 * h) * 224 + 2 * w];
  int t1 = it[(2 * h) * 224 + 2 * w + 1];
  int t2 = it[(2 * h + 1) * 224 + 2 * w];
  int t3 = it[(2 * h + 1) * 224 + 2 * w + 1];
  const float* base = kv_x + (long)b * 12544 * 128 + c0;
  const float recip = 1.0f / (4.0f + 1e-6f);
  float4 a0 = *(const float4*)(base + (long)t0 * 128);
  float4 a1 = *(const float4*)(base + (long)t1 * 128);
  float4 a2 = *(const float4*)(base + (long)t2 * 128);
  float4 a3 = *(const float4*)(base + (long)t3 * 128);
  u16x4 o;
  o[0] = f2b((a0.x + a1.x + a2.x + a3.x) * recip);
  o[1] = f2b((a0.y + a1.y + a2.y + a3.y) * recip);
  o[2] = f2b((a0.z + a1.z + a2.z + a3.z) * recip);
  o[3] = f2b((a0.w + a1.w + a2.w + a3.w) * recip);
  *(u16x4*)(kv_map + (long)cell * 128 + c0) = o;
  if ((tid & 31) == 0) {
    const float* ts = tsc + b * 12544;
    conf_map[cell] = (ts[t0] + ts[t1] + ts[t2] + ts[t3]) * recip;
  }
}

// ---------------- conv (patch GEMM, A+B staged) + LayerNorm + kv projection ----------------
__launch_bounds__(256)
__global__ void k_conv_ln_kv(const unsigned short* __restrict__ kv_map,
                             const unsigned short* __restrict__ srwt,
                             const float* __restrict__ srb, const float* __restrict__ ng,
                             const float* __restrict__ nb,
                             const unsigned short* __restrict__ kvwt,
                             unsigned short* __restrict__ kbuf,
                             unsigned short* __restrict__ vbuf,
                             const float* __restrict__ conf_map, float* __restrict__ conf) {
  __shared__ unsigned short At[64 * 136];
  __shared__ unsigned short Bt[128 * 136];
  const int tid = threadIdx.x;
  const int lane = tid & 63, w = tid >> 6;
  const int l15 = lane & 15, g = lane >> 4;
  const int r0 = blockIdx.x * 64;
  if (tid < 64) {
    int pos = r0 + tid;
    int bq = pos / 784, p2 = pos - bq * 784;
    int oh = p2 / 28, ow = p2 - oh * 28;
    float s = 0.f;
#pragma unroll
    for (int kh = 0; kh < 4; kh++)
#pragma unroll
      for (int kw = 0; kw < 4; kw++)
        s += conf_map[bq * 12544 + (4 * oh + kh) * 112 + 4 * ow + kw];
    conf[bq * NSP + p2] = s * (LOG2E / 16.0f);
  }
  const f4 fz = {0.f, 0.f, 0.f, 0.f};
  f4 acc[8];
#pragma unroll
  for (int i = 0; i < 8; i++) acc[i] = fz;

  for (int p = 0; p < 16; p++) {
#pragma unroll
    for (int j = 0; j < 4; j++) {
      int id = tid + 256 * j;
      int row = id >> 4, c0 = (id & 15) << 3;
      int rr = r0 + row;
      int bb = rr / 784, pos = rr - bb * 784;
      int oh = pos / 28, ow = pos - oh * 28;
      long src = ((long)(bb * 12544 + (4 * oh + (p >> 2)) * 112 + 4 * ow + (p & 3))) * 128 + c0;
      *(uint4*)(At + row * 136 + c0) = *(const uint4*)(kv_map + src);
    }
#pragma unroll
    for (int j = 0; j < 8; j++) {
      int id = tid + 256 * j;
      int row = id >> 4, c0 = (id & 15) << 3;
      *(uint4*)(Bt + row * 136 + c0) = *(const uint4*)(srwt + row * 2048 + p * 128 + c0);
    }
    __syncthreads();
#pragma unroll
    for (int ks = 0; ks < 4; ks++) {
      bf8 a = ldfrag(At, 136, 16 * w, 32 * ks);
#pragma unroll
      for (int nf = 0; nf < 8; nf++) {
        bf8 bb = ldfrag(Bt, 136, 16 * nf, 32 * ks);
        acc[nf] = MFMA16(a, bb, acc[nf]);
      }
    }
    __syncthreads();
  }
  float sum_[4] = {0.f, 0.f, 0.f, 0.f}, sq_[4] = {0.f, 0.f, 0.f, 0.f};
#pragma unroll
  for (int nf = 0; nf < 8; nf++) {
    float bias = srb[16 * nf + l15];
#pragma unroll
    for (int reg = 0; reg < 4; reg++) {
      float v = acc[nf][reg] + bias;
      acc[nf][reg] = v;
      sum_[reg] += v;
      sq_[reg] += v * v;
    }
  }
#pragma unroll
  for (int msk = 1; msk < 16; msk <<= 1)
#pragma unroll
    for (int reg = 0; reg < 4; reg++) {
      sum_[reg] += __shfl_xor(sum_[reg], msk, 64);
      sq_[reg] += __shfl_xor(sq_[reg], msk, 64);
    }
#pragma unroll
  for (int nf = 0; nf < 8; nf++) {
    float gc = ng[16 * nf + l15], bc = nb[16 * nf + l15];
#pragma unroll
    for (int reg = 0; reg < 4; reg++) {
      float mean = sum_[reg] * (1.0f / 128.0f);
      float var = sq_[reg] * (1.0f / 128.0f) - mean * mean;
      float v = (acc[nf][reg] - mean) * rsqrtf(var + 1e-5f) * gc + bc;
      At[(16 * w + 4 * g + reg) * 136 + 16 * nf + l15] = f2b(v);
    }
  }
  __syncthreads();
  f4 acc2[16];
#pragma unroll
  for (int i = 0; i < 16; i++) acc2[i] = fz;
#pragma unroll
  for (int ks = 0; ks < 4; ks++) {
    bf8 a = ldfrag(At, 136, 16 * w, 32 * ks);
#pragma unroll
    for (int nf = 0; nf < 16; nf++) {
      bf8 bb = *(const bf8*)(kvwt + (16 * nf + l15) * 128 + 32 * ks + (g << 3));
      acc2[nf] = MFMA16(a, bb, acc2[nf]);
    }
  }
#pragma unroll
  for (int nf = 0; nf < 16; nf++)
#pragma unroll
    for (int reg = 0; reg < 4; reg++) {
      int r = r0 + 16 * w + 4 * g + reg;
      int b = r / 784, ns = r - b * 784;
      int j = 16 * nf + l15;
      int sel = j >> 7, hh = (j >> 6) & 1, d = j & 63;
      unsigned short val = f2b(acc2[nf][reg]);
      if (sel == 0) kbuf[((long)(b * 2 + hh) * NSP + ns) * 64 + d] = val;
      else          vbuf[((long)(b * 2 + hh) * 64 + d) * NSP + ns] = val;
    }
}

// ---------------- q GEMM (A+B staged, XCD-swizzled per batch) ----------------
__launch_bounds__(256)
__global__ void k_q(const float* __restrict__ q_x, const unsigned short* __restrict__ qwt,
                    unsigned short* __restrict__ qbuf) {
  __shared__ unsigned short At[64 * 136];
  __shared__ unsigned short Bt[128 * 136];
  const int tid = threadIdx.x;
  const int lane = tid & 63, w = tid >> 6;
  const int l15 = lane & 15, g = lane >> 4;
  const int bid = blockIdx.x;
  const int r0 = (bid & 7) * NQTOK + (bid >> 3) * 64;   // batch (bid&7) on XCD (bid&7)
#pragma unroll
  for (int j = 0; j < 8; j++) {
    int id = tid + 256 * j;
    int row = id >> 5, c0 = (id & 31) << 2;
    float4 v = *(const float4*)(q_x + (long)(r0 + row) * 128 + c0);
    u16x4 o;
    o[0] = f2b(v.x); o[1] = f2b(v.y); o[2] = f2b(v.z); o[3] = f2b(v.w);
    *(u16x4*)(At + row * 136 + c0) = o;
  }
#pragma unroll
  for (int j = 0; j < 8; j++) {
    int id = tid + 256 * j;
    int row = id >> 4, c0 = (id & 15) << 3;
    *(uint4*)(Bt + row * 136 + c0) = *(const uint4*)(qwt + (long)row * 128 + c0);
  }
  __syncthreads();
  const f4 fz = {0.f, 0.f, 0.f, 0.f};
  f4 acc[8];
#pragma unroll
  for (int i = 0; i < 8; i++) acc[i] = fz;
#pragma unroll
  for (int ks = 0; ks < 4; ks++) {
    bf8 a = ldfrag(At, 136, 16 * w, 32 * ks);
#pragma unroll
    for (int nf = 0; nf < 8; nf++) {
      bf8 bb = ldfrag(Bt, 136, 16 * nf, 32 * ks);
      acc[nf] = MFMA16(a, bb, acc[nf]);
    }
  }
#pragma unroll
  for (int nf = 0; nf < 8; nf++)
#pragma unroll
    for (int reg = 0; reg < 4; reg++) {
      int r = r0 + 16 * w + 4 * g + reg;
      int b = r / NQTOK, n = r - b * NQTOK;
      int j = 16 * nf + l15;
      int hh = j >> 6, d = j & 63;
      qbuf[((long)(b * 2 + hh) * NQTOK + n) * 64 + d] = f2b(acc[nf][reg]);
    }
}

// ---------------- flash attention (XCD swizzle, conf-C, JIT V-frags) ----------------
__launch_bounds__(256, 3)
__global__ void k_attn(const unsigned short* __restrict__ qbuf,
                       const unsigned short* __restrict__ kbuf,
                       const unsigned short* __restrict__ vbuf,
                       const float* __restrict__ conf,
                       unsigned short* __restrict__ attbuf) {
  __shared__ unsigned short Kt[2][64 * 72];   // [kv][d], stride 72
  __shared__ unsigned short Vt[2][64 * 72];   // [d][kv], stride 72
  const int tid = threadIdx.x;
  const int lane = tid & 63, w = tid >> 6;
  const int l15 = lane & 15, g = lane >> 4;
  // XCD swizzle: grid 1568 = 8 XCDs x 196; each XCD owns 2 bh (K/V L2-resident)
  const int bid = blockIdx.x;
  const int xcd = bid & 7, idx = bid >> 3;    // idx 0..195
  const int sub = idx / 98;                   // 0..1
  const int xb = idx - sub * 98;
  const int bhid = xcd * 2 + sub;             // 0..15
  const int b = bhid >> 1, h = bhid & 1;
  const int bh = b * 2 + h;
  const int q0 = xb * 128 + 32 * w;           // this wave's 32 q rows

  const unsigned short* qsrc = qbuf + ((long)bh * NQTOK + q0) * 64;
  bf8 qf[2][2];
#pragma unroll
  for (int mr = 0; mr < 2; mr++)
#pragma unroll
    for (int ks = 0; ks < 2; ks++)
      qf[mr][ks] = *(const bf8*)(qsrc + (16 * mr + l15) * 64 + 32 * ks + (g << 3));

  const int srow = tid >> 2;
  const int scol = (tid & 3) << 4;
  const unsigned short* kg = kbuf + (long)bh * NSP * 64 + srow * 64 + scol;
  const unsigned short* vg = vbuf + (long)bh * 64 * NSP + (long)srow * NSP + scol;
  unsigned short* klds = &Kt[0][0] + srow * 72 + scol;
  unsigned short* vlds = &Vt[0][0] + srow * 72 + scol;

  uint4 kr0, kr1, vr0, vr1;
#define ISSUE(T)                                                   \
  do {                                                             \
    const unsigned short* kp_ = kg + (long)(T) * 4096;             \
    const unsigned short* vp_ = vg + (T) * 64;                     \
    kr0 = *(const uint4*)(kp_);                                    \
    kr1 = *(const uint4*)(kp_ + 8);                                \
    vr0 = *(const uint4*)(vp_);                                    \
    vr1 = *(const uint4*)(vp_ + 8);                                \
  } while (0)
#define STWRITE(BUF)                                               \
  do {                                                             \
    unsigned short* kd_ = klds + (BUF) * 4608;                     \
    unsigned short* vd_ = vlds + (BUF) * 4608;                     \
    *(uint4*)kd_ = kr0;  *(uint4*)(kd_ + 8) = kr1;                 \
    *(uint4*)vd_ = vr0;  *(uint4*)(vd_ + 8) = vr1;                 \
  } while (0)

  ISSUE(0);
  STWRITE(0);
  ISSUE(1);
  __syncthreads();

  const f4 fz = {0.f, 0.f, 0.f, 0.f};
  f4 ao[2][4], aol[2];
#pragma unroll
  for (int mr = 0; mr < 2; mr++) {
    aol[mr] = fz;
#pragma unroll
    for (int i = 0; i < 4; i++) ao[mr][i] = fz;
  }
  const short on = (short)0x3F80;                  // bf16 1.0
  const bf8 onesf = {on, on, on, on, on, on, on, on};
  const float* confb = conf + b * NSP;

#pragma unroll 2
  for (int t = 0; t < 13; t++) {
    const int cur = t & 1;
    const unsigned short* KtB = &Kt[cur][0];
    const unsigned short* VtB = &Vt[cur][0];
    bf8 kf[4][2];
#pragma unroll
    for (int mf = 0; mf < 4; mf++)
#pragma unroll
      for (int ks = 0; ks < 2; ks++)
        kf[mf][ks] = ldfrag(KtB, 72, 16 * mf, 32 * ks);
    // conf as MFMA C-operand: C row = kv = 16mf+4g+reg, q-uniform across cols
    f4 cvi[4];
#pragma unroll
    for (int mf = 0; mf < 4; mf++) {
      float4 cv = *(const float4*)(confb + t * 64 + 16 * mf + 4 * g);
      cvi[mf][0] = cv.x; cvi[mf][1] = cv.y; cvi[mf][2] = cv.z; cvi[mf][3] = cv.w;
    }
#pragma unroll
    for (int mr = 0; mr < 2; mr++) {
      f4 s_[4];
#pragma unroll
      for (int mf = 0; mf < 4; mf++)
        s_[mf] = MFMA16(kf[mf][0], qf[mr][0], cvi[mf]);   // C-in = conf, no copy
#pragma unroll
      for (int mf = 0; mf < 4; mf++)
        s_[mf] = MFMA16(kf[mf][1], qf[mr][1], s_[mf]);
      unsigned W[4][2];
#pragma unroll
      for (int mf = 0; mf < 4; mf++) {
        float p0 = EXP2(s_[mf][0]);
        float p1 = EXP2(s_[mf][1]);
        float p2 = EXP2(s_[mf][2]);
        float p3 = EXP2(s_[mf][3]);
        W[mf][0] = pk2(p0, p1);
        W[mf][1] = pk2(p2, p3);
      }
      // PV with just-in-time V-frags: keeps V out of the resident register set
#pragma unroll
      for (int ks = 0; ks < 2; ks++) {
        bf8 pa = rows2frag(W[2 * ks], W[2 * ks + 1]);
        aol[mr] = MFMA16(pa, onesf, aol[mr]);
#pragma unroll
        for (int nfd = 0; nfd < 4; nfd++) {
          bf8 vf = ldfrag(VtB, 72, 16 * nfd, 32 * ks);
          ao[mr][nfd] = MFMA16(pa, vf, ao[mr][nfd]);
        }
      }
    }
    if (t < 12) STWRITE(cur ^ 1);
    if (t < 11) ISSUE(t + 2);
    __syncthreads();
  }
#undef ISSUE
#undef STWRITE
#pragma unroll
  for (int mr = 0; mr < 2; mr++) {
    float inv[4];
#pragma unroll
    for (int reg = 0; reg < 4; reg++) inv[reg] = 1.0f / aol[mr][reg];
#pragma unroll
    for (int nfd = 0; nfd < 4; nfd++)
#pragma unroll
      for (int reg = 0; reg < 4; reg++) {
        int n = q0 + 16 * mr + 4 * g + reg;
        int col = h * 64 + 16 * nfd + l15;
        attbuf[((long)b * NQTOK + n) * 128 + col] = f2b(ao[mr][nfd][reg] * inv[reg]);
      }
  }
}

// ---------------- final projection (A+B staged, XCD-swizzled per batch) ----------------
__launch_bounds__(256)
__global__ void k_proj(const unsigned short* __restrict__ attbuf,
                       const unsigned short* __restrict__ pwt,
                       const float* __restrict__ pb, float* __restrict__ out) {
  __shared__ unsigned short At[64 * 136];
  __shared__ unsigned short Bt[128 * 136];
  const int tid = threadIdx.x;
  const int lane = tid & 63, w = tid >> 6;
  const int l15 = lane & 15, g = lane >> 4;
  const int bid = blockIdx.x;
  const int r0 = (bid & 7) * NQTOK + (bid >> 3) * 64;   // batch (bid&7) on XCD (bid&7)
#pragma unroll
  for (int j = 0; j < 4; j++) {
    int id = tid + 256 * j;
    int row = id >> 4, c0 = (id & 15) << 3;
    *(uint4*)(At + row * 136 + c0) = *(const uint4*)(attbuf + (long)(r0 + row) * 128 + c0);
  }
#pragma unroll
  for (int j = 0; j < 8; j++) {
    int id = tid + 256 * j;
    int row = id >> 4, c0 = (id & 15) << 3;
    *(uint4*)(Bt + row * 136 + c0) = *(const uint4*)(pwt + (long)row * 128 + c0);
  }
  __syncthreads();
  const f4 fz = {0.f, 0.f, 0.f, 0.f};
  f4 acc[8];
#pragma unroll
  for (int i = 0; i < 8; i++) acc[i] = fz;
#pragma unroll
  for (int ks = 0; ks < 4; ks++) {
    bf8 a = ldfrag(At, 136, 16 * w, 32 * ks);
#pragma unroll
    for (int nf = 0; nf < 8; nf++) {
      bf8 bb = ldfrag(Bt, 136, 16 * nf, 32 * ks);
      acc[nf] = MFMA16(a, bb, acc[nf]);
    }
  }
#pragma unroll
  for (int nf = 0; nf < 8; nf++) {
    float bias = pb[16 * nf + l15];
#pragma unroll
    for (int reg = 0; reg < 4; reg++) {
      int r = r0 + 16 * w + 4 * g + reg;
      out[(long)r * 128 + 16 * nf + l15] = acc[nf][reg] + bias;
    }
  }
}

extern "C" void kernel_launch(void* const* d_in, const int* in_sizes, int n_in,
                              void* d_out, int out_size, void* d_ws, size_t ws_size,
                              hipStream_t stream) {
  const float* q_x  = (const float*)d_in[0];
  const float* kv_x = (const float*)d_in[1];
  const float* tsc  = (const float*)d_in[2];
  const int*   idxt = (const int*)d_in[3];
  const float* q_w  = (const float*)d_in[8];
  const float* kv_w = (const float*)d_in[9];
  const float* pw   = (const float*)d_in[10];
  const float* pb   = (const float*)d_in[11];
  const float* srw  = (const float*)d_in[12];
  const float* srb  = (const float*)d_in[13];
  const float* ng   = (const float*)d_in[14];
  const float* nb   = (const float*)d_in[15];
  float* outp = (float*)d_out;

  char* ws = (char*)d_ws;
  size_t off = 0;
  auto take = [&](size_t bytes) {
    char* p = ws + off;
    off += (bytes + 255) & ~(size_t)255;
    return p;
  };
  unsigned short* qwt   = (unsigned short*)take(128 * 128 * 2);
  unsigned short* pwt   = (unsigned short*)take(128 * 128 * 2);
  unsigned short* kvwt  = (unsigned short*)take(256 * 128 * 2);
  unsigned short* srwt  = (unsigned short*)take(128 * 2048 * 2);
  unsigned short* kvmap = (unsigned short*)take((size_t)NBATCH * 12544 * 128 * 2);
  float* conf_map       = (float*)take((size_t)NBATCH * 12544 * 4);
  unsigned short* kbuf  = (unsigned short*)take((size_t)NBATCH * 2 * NSP * 64 * 2);
  unsigned short* vbuf  = (unsigned short*)take((size_t)NBATCH * 2 * NSP * 64 * 2);
  float* conf           = (float*)take((size_t)NBATCH * NSP * 4);
  unsigned short* qbuf  = (unsigned short*)take((size_t)NBATCH * 2 * NQTOK * 64 * 2);
  unsigned short* attbuf = kvmap;  // kv_map dead after k_conv_ln_kv

  k_token2map<<<12800, 256, 0, stream>>>(kv_x, tsc, idxt, kvmap, conf_map,
                                         q_w, kv_w, pw, srw, qwt, kvwt, pwt, srwt,
                                         (unsigned*)kbuf, (unsigned*)vbuf, conf);
  k_conv_ln_kv<<<98, 256, 0, stream>>>(kvmap, srwt, srb, ng, nb, kvwt, kbuf, vbuf,
                                       conf_map, conf);
  k_q<<<1568, 256, 0, stream>>>(q_x, qwt, qbuf);
  k_attn<<<1568, 256, 0, stream>>>(qbuf, kbuf, vbuf, conf, attbuf);
  k_proj<<<1568, 256, 0, stream>>>(attbuf, pwt, pb, outp);
}

// Round 17
// 151.648 us; speedup vs baseline: 1.6385x; 1.0045x over previous
//
#include <hip/hip_runtime.h>
#include <hip/hip_bf16.h>

// TCFormer dynamic attention, MI355X. R16 config + full k_attn register diet.
//  k_token2map:  gather-average 4 tokens/cell -> kv_map bf16, conf_map f32.
//                XCD-swizzled (b = bid&7). Tail 256 blocks do weight setup.
//  k_conv_ln_kv: conv as MFMA GEMM, A+B LDS-staged + LayerNorm -> LDS -> kv proj
//                (B direct from 64KB kvwt ok); + conf pool
//  k_q:          q_x @ qwt -> qbuf, A+B LDS-staged, XCD-swizzled per batch
//  k_attn:       flash attn, 256 thr, 1 head/block, 128 q rows, K/V LDS
//                double-buffer, single barrier/tile, swapped QK^T, conf folded
//                into first-MFMA C-init, v_exp_f32, l via ones-MFMA, XCD swizzle.
//                K AND V frags loaded JUST-IN-TIME (transient): R16 showed the
//                resident vf[4][2] was spilling ~19MB/dispatch; JIT-V cut attn
//                77->67us. This round makes kf transient too (mf-major QK loop,
//                same 8 ds_reads/tile) to kill the remaining ~5MB of spills.
//  k_proj:       attbuf @ proj_w + proj_b -> f32 out, A+B staged, XCD-swizzled
//  REGISTER LESSON (R7+R10): launch_bounds arg2 is waves/EU; over-requesting
//  spills ~600MB scratch. FUSION LESSON (R12): don't fuse LDS-heavy work into
//  latency-bound kernels. STAGING LESSON (R13/R14): MFMA B-operands from LDS.

#define NBATCH 8
#define NQTOK  12544
#define NSP    832
#define LOG2E  1.4426950408889634f
#define QSCALE (0.125f * LOG2E)

typedef __attribute__((ext_vector_type(8))) short bf8;
typedef __attribute__((ext_vector_type(4))) float f4;
typedef __attribute__((ext_vector_type(4))) unsigned short u16x4;
typedef __attribute__((ext_vector_type(2))) unsigned int u32x2;

#define MFMA16(a, b, c) __builtin_amdgcn_mfma_f32_16x16x32_bf16((a), (b), (c), 0, 0, 0)

#if __has_builtin(__builtin_amdgcn_exp2f)
#define EXP2(x) __builtin_amdgcn_exp2f(x)
#else
#define EXP2(x) exp2f(x)
#endif

__device__ __forceinline__ unsigned short f2b(float x) {
  union { float f; unsigned u; } v; v.f = x;
  unsigned r = v.u + 0x7FFFu + ((v.u >> 16) & 1u);
  return (unsigned short)(r >> 16);
}

__device__ __forceinline__ unsigned pk2(float lo, float hi) {
  float2 t; t.x = lo; t.y = hi;
  __hip_bfloat162 bb = __float22bfloat162_rn(t);
  union { __hip_bfloat162 b; unsigned u; } v; v.b = bb;
  return v.u;
}

// Row-layout reg pairs (rows 16mf+4g+reg, passthrough col l15) -> 8-wide-k frag.
__device__ __forceinline__ bf8 rows2frag(const unsigned W0[2], const unsigned W1[2]) {
  u32x2 r0 = __builtin_amdgcn_permlane32_swap(W0[0], W1[0], false, false);
  u32x2 t02 = __builtin_amdgcn_permlane16_swap(r0.x, r0.y, false, false);
  u32x2 r1 = __builtin_amdgcn_permlane32_swap(W0[1], W1[1], false, false);
  u32x2 t13 = __builtin_amdgcn_permlane16_swap(r1.x, r1.y, false, false);
  union { unsigned u[4]; bf8 v; } pa;
  pa.u[0] = t02.x; pa.u[1] = t13.x; pa.u[2] = t02.y; pa.u[3] = t13.y;
  return pa.v;
}

// lane holds tile[rbase + (lane&15)][kbase + 8*(lane>>4) .. +7]
__device__ __forceinline__ bf8 ldfrag(const unsigned short* t, int stride, int rbase, int kbase) {
  int lane = threadIdx.x & 63;
  return *(const bf8*)(t + (rbase + (lane & 15)) * stride + kbase + ((lane >> 4) << 3));
}

// ---------------- token2map (XCD-swizzled) + fused weight setup ----------------
__global__ void k_token2map(const float* __restrict__ kv_x, const float* __restrict__ tsc,
                            const int* __restrict__ idxt,
                            unsigned short* __restrict__ kv_map, float* __restrict__ conf_map,
                            const float* __restrict__ qw, const float* __restrict__ kvw,
                            const float* __restrict__ pw, const float* __restrict__ srw,
                            unsigned short* __restrict__ qwt, unsigned short* __restrict__ kvwt,
                            unsigned short* __restrict__ pwt, unsigned short* __restrict__ srwt,
                            unsigned* __restrict__ kb, unsigned* __restrict__ vb,
                            float* __restrict__ conf) {
  int tid = threadIdx.x;
  int bid = blockIdx.x;
  if (bid >= 12544) {                              // setup tail: 256 blocks
    int t = (bid - 12544) * 256 + tid;
    int nt = 256 * 256;
    for (int i = t; i < 128 * 128; i += nt) {
      int k = i >> 7, n = i & 127;
      qwt[n * 128 + k] = f2b(qw[k * 128 + n] * QSCALE);
      pwt[n * 128 + k] = f2b(pw[k * 128 + n]);
    }
    for (int i = t; i < 128 * 256; i += nt) {
      int k = i >> 8, j = i & 255;
      kvwt[j * 128 + k] = f2b(kvw[k * 256 + j]);
    }
    for (int i = t; i < 128 * 2048; i += nt) {
      int o = i >> 11, kk = i & 2047;
      int p = kk >> 7, c = kk & 127;
      srwt[o * 2048 + kk] = f2b(srw[o * 2048 + c * 16 + p]);
    }
    const int nu = NBATCH * 2 * NSP * 64 / 2;
    for (int i = t; i < nu; i += nt) { kb[i] = 0u; vb[i] = 0u; }
    for (int i = t; i < NBATCH * NSP; i += nt) conf[i] = -1e30f;
    return;
  }
  int b = bid & 7, pos = bid >> 3;                 // 1568 blocks/batch on one XCD
  int hw = pos * 8 + (tid >> 5);
  int cell = b * 12544 + hw;
  int c0 = (tid & 31) << 2;
  int h = hw / 112, w = hw - h * 112;
  const int* it = idxt + b * 50176;
  int t0 = it[(2 * h) * 224 + 2 * w];
  int t1 = it[(2 * h) * 224 + 2 * w + 1];
  int t2 = it[(2 * h + 1) * 224 + 2 * w];
  int t3 = it[(2 * h + 1) * 224 + 2 * w + 1];
  const float* base = kv_x + (long)b * 12544 * 128 + c0;
  const float recip = 1.0f / (4.0f + 1e-6f);
  float4 a0 = *(const float4*)(base + (long)t0 * 128);
  float4 a1 = *(const float4*)(base + (long)t1 * 128);
  float4 a2 = *(const float4*)(base + (long)t2 * 128);
  float4 a3 = *(const float4*)(base + (long)t3 * 128);
  u16x4 o;
  o[0] = f2b((a0.x + a1.x + a2.x + a3.x) * recip);
  o[1] = f2b((a0.y + a1.y + a2.y + a3.y) * recip);
  o[2] = f2b((a0.z + a1.z + a2.z + a3.z) * recip);
  o[3] = f2b((a0.w + a1.w + a2.w + a3.w) * recip);
  *(u16x4*)(kv_map + (long)cell * 128 + c0) = o;
  if ((tid & 31) == 0) {
    const float* ts = tsc + b * 12544;
    conf_map[cell] = (ts[t0] + ts[t1] + ts[t2] + ts[t3]) * recip;
  }
}

// ---------------- conv (patch GEMM, A+B staged) + LayerNorm + kv projection ----------------
__launch_bounds__(256)
__global__ void k_conv_ln_kv(const unsigned short* __restrict__ kv_map,
                             const unsigned short* __restrict__ srwt,
                             const float* __restrict__ srb, const float* __restrict__ ng,
                             const float* __restrict__ nb,
                             const unsigned short* __restrict__ kvwt,
                             unsigned short* __restrict__ kbuf,
                             unsigned short* __restrict__ vbuf,
                             const float* __restrict__ conf_map, float* __restrict__ conf) {
  __shared__ unsigned short At[64 * 136];
  __shared__ unsigned short Bt[128 * 136];
  const int tid = threadIdx.x;
  const int lane = tid & 63, w = tid >> 6;
  const int l15 = lane & 15, g = lane >> 4;
  const int r0 = blockIdx.x * 64;
  if (tid < 64) {
    int pos = r0 + tid;
    int bq = pos / 784, p2 = pos - bq * 784;
    int oh = p2 / 28, ow = p2 - oh * 28;
    float s = 0.f;
#pragma unroll
    for (int kh = 0; kh < 4; kh++)
#pragma unroll
      for (int kw = 0; kw < 4; kw++)
        s += conf_map[bq * 12544 + (4 * oh + kh) * 112 + 4 * ow + kw];
    conf[bq * NSP + p2] = s * (LOG2E / 16.0f);
  }
  const f4 fz = {0.f, 0.f, 0.f, 0.f};
  f4 acc[8];
#pragma unroll
  for (int i = 0; i < 8; i++) acc[i] = fz;

  for (int p = 0; p < 16; p++) {
#pragma unroll
    for (int j = 0; j < 4; j++) {
      int id = tid + 256 * j;
      int row = id >> 4, c0 = (id & 15) << 3;
      int rr = r0 + row;
      int bb = rr / 784, pos = rr - bb * 784;
      int oh = pos / 28, ow = pos - oh * 28;
      long src = ((long)(bb * 12544 + (4 * oh + (p >> 2)) * 112 + 4 * ow + (p & 3))) * 128 + c0;
      *(uint4*)(At + row * 136 + c0) = *(const uint4*)(kv_map + src);
    }
#pragma unroll
    for (int j = 0; j < 8; j++) {
      int id = tid + 256 * j;
      int row = id >> 4, c0 = (id & 15) << 3;
      *(uint4*)(Bt + row * 136 + c0) = *(const uint4*)(srwt + row * 2048 + p * 128 + c0);
    }
    __syncthreads();
#pragma unroll
    for (int ks = 0; ks < 4; ks++) {
      bf8 a = ldfrag(At, 136, 16 * w, 32 * ks);
#pragma unroll
      for (int nf = 0; nf < 8; nf++) {
        bf8 bb = ldfrag(Bt, 136, 16 * nf, 32 * ks);
        acc[nf] = MFMA16(a, bb, acc[nf]);
      }
    }
    __syncthreads();
  }
  float sum_[4] = {0.f, 0.f, 0.f, 0.f}, sq_[4] = {0.f, 0.f, 0.f, 0.f};
#pragma unroll
  for (int nf = 0; nf < 8; nf++) {
    float bias = srb[16 * nf + l15];
#pragma unroll
    for (int reg = 0; reg < 4; reg++) {
      float v = acc[nf][reg] + bias;
      acc[nf][reg] = v;
      sum_[reg] += v;
      sq_[reg] += v * v;
    }
  }
#pragma unroll
  for (int msk = 1; msk < 16; msk <<= 1)
#pragma unroll
    for (int reg = 0; reg < 4; reg++) {
      sum_[reg] += __shfl_xor(sum_[reg], msk, 64);
      sq_[reg] += __shfl_xor(sq_[reg], msk, 64);
    }
#pragma unroll
  for (int nf = 0; nf < 8; nf++) {
    float gc = ng[16 * nf + l15], bc = nb[16 * nf + l15];
#pragma unroll
    for (int reg = 0; reg < 4; reg++) {
      float mean = sum_[reg] * (1.0f / 128.0f);
      float var = sq_[reg] * (1.0f / 128.0f) - mean * mean;
      float v = (acc[nf][reg] - mean) * rsqrtf(var + 1e-5f) * gc + bc;
      At[(16 * w + 4 * g + reg) * 136 + 16 * nf + l15] = f2b(v);
    }
  }
  __syncthreads();
  f4 acc2[16];
#pragma unroll
  for (int i = 0; i < 16; i++) acc2[i] = fz;
#pragma unroll
  for (int ks = 0; ks < 4; ks++) {
    bf8 a = ldfrag(At, 136, 16 * w, 32 * ks);
#pragma unroll
    for (int nf = 0; nf < 16; nf++) {
      bf8 bb = *(const bf8*)(kvwt + (16 * nf + l15) * 128 + 32 * ks + (g << 3));
      acc2[nf] = MFMA16(a, bb, acc2[nf]);
    }
  }
#pragma unroll
  for (int nf = 0; nf < 16; nf++)
#pragma unroll
    for (int reg = 0; reg < 4; reg++) {
      int r = r0 + 16 * w + 4 * g + reg;
      int b = r / 784, ns = r - b * 784;
      int j = 16 * nf + l15;
      int sel = j >> 7, hh = (j >> 6) & 1, d = j & 63;
      unsigned short val = f2b(acc2[nf][reg]);
      if (sel == 0) kbuf[((long)(b * 2 + hh) * NSP + ns) * 64 + d] = val;
      else          vbuf[((long)(b * 2 + hh) * 64 + d) * NSP + ns] = val;
    }
}

// ---------------- q GEMM (A+B staged, XCD-swizzled per batch) ----------------
__launch_bounds__(256)
__global__ void k_q(const float* __restrict__ q_x, const unsigned short* __restrict__ qwt,
                    unsigned short* __restrict__ qbuf) {
  __shared__ unsigned short At[64 * 136];
  __shared__ unsigned short Bt[128 * 136];
  const int tid = threadIdx.x;
  const int lane = tid & 63, w = tid >> 6;
  const int l15 = lane & 15, g = lane >> 4;
  const int bid = blockIdx.x;
  const int r0 = (bid & 7) * NQTOK + (bid >> 3) * 64;   // batch (bid&7) on XCD (bid&7)
#pragma unroll
  for (int j = 0; j < 8; j++) {
    int id = tid + 256 * j;
    int row = id >> 5, c0 = (id & 31) << 2;
    float4 v = *(const float4*)(q_x + (long)(r0 + row) * 128 + c0);
    u16x4 o;
    o[0] = f2b(v.x); o[1] = f2b(v.y); o[2] = f2b(v.z); o[3] = f2b(v.w);
    *(u16x4*)(At + row * 136 + c0) = o;
  }
#pragma unroll
  for (int j = 0; j < 8; j++) {
    int id = tid + 256 * j;
    int row = id >> 4, c0 = (id & 15) << 3;
    *(uint4*)(Bt + row * 136 + c0) = *(const uint4*)(qwt + (long)row * 128 + c0);
  }
  __syncthreads();
  const f4 fz = {0.f, 0.f, 0.f, 0.f};
  f4 acc[8];
#pragma unroll
  for (int i = 0; i < 8; i++) acc[i] = fz;
#pragma unroll
  for (int ks = 0; ks < 4; ks++) {
    bf8 a = ldfrag(At, 136, 16 * w, 32 * ks);
#pragma unroll
    for (int nf = 0; nf < 8; nf++) {
      bf8 bb = ldfrag(Bt, 136, 16 * nf, 32 * ks);
      acc[nf] = MFMA16(a, bb, acc[nf]);
    }
  }
#pragma unroll
  for (int nf = 0; nf < 8; nf++)
#pragma unroll
    for (int reg = 0; reg < 4; reg++) {
      int r = r0 + 16 * w + 4 * g + reg;
      int b = r / NQTOK, n = r - b * NQTOK;
      int j = 16 * nf + l15;
      int hh = j >> 6, d = j & 63;
      qbuf[((long)(b * 2 + hh) * NQTOK + n) * 64 + d] = f2b(acc[nf][reg]);
    }
}

// ---------------- flash attention (XCD swizzle, conf-C, JIT K+V frags) ----------------
__launch_bounds__(256, 3)
__global__ void k_attn(const unsigned short* __restrict__ qbuf,
                       const unsigned short* __restrict__ kbuf,
                       const unsigned short* __restrict__ vbuf,
                       const float* __restrict__ conf,
                       unsigned short* __restrict__ attbuf) {
  __shared__ unsigned short Kt[2][64 * 72];   // [kv][d], stride 72
  __shared__ unsigned short Vt[2][64 * 72];   // [d][kv], stride 72
  const int tid = threadIdx.x;
  const int lane = tid & 63, w = tid >> 6;
  const int l15 = lane & 15, g = lane >> 4;
  // XCD swizzle: grid 1568 = 8 XCDs x 196; each XCD owns 2 bh (K/V L2-resident)
  const int bid = blockIdx.x;
  const int xcd = bid & 7, idx = bid >> 3;    // idx 0..195
  const int sub = idx / 98;                   // 0..1
  const int xb = idx - sub * 98;
  const int bhid = xcd * 2 + sub;             // 0..15
  const int b = bhid >> 1, h = bhid & 1;
  const int bh = b * 2 + h;
  const int q0 = xb * 128 + 32 * w;           // this wave's 32 q rows

  const unsigned short* qsrc = qbuf + ((long)bh * NQTOK + q0) * 64;
  bf8 qf[2][2];
#pragma unroll
  for (int mr = 0; mr < 2; mr++)
#pragma unroll
    for (int ks = 0; ks < 2; ks++)
      qf[mr][ks] = *(const bf8*)(qsrc + (16 * mr + l15) * 64 + 32 * ks + (g << 3));

  const int srow = tid >> 2;
  const int scol = (tid & 3) << 4;
  const unsigned short* kg = kbuf + (long)bh * NSP * 64 + srow * 64 + scol;
  const unsigned short* vg = vbuf + (long)bh * 64 * NSP + (long)srow * NSP + scol;
  unsigned short* klds = &Kt[0][0] + srow * 72 + scol;
  unsigned short* vlds = &Vt[0][0] + srow * 72 + scol;

  uint4 kr0, kr1, vr0, vr1;
#define ISSUE(T)                                                   \
  do {                                                             \
    const unsigned short* kp_ = kg + (long)(T) * 4096;             \
    const unsigned short* vp_ = vg + (T) * 64;                     \
    kr0 = *(const uint4*)(kp_);                                    \
    kr1 = *(const uint4*)(kp_ + 8);                                \
    vr0 = *(const uint4*)(vp_);                                    \
    vr1 = *(const uint4*)(vp_ + 8);                                \
  } while (0)
#define STWRITE(BUF)                                               \
  do {                                                             \
    unsigned short* kd_ = klds + (BUF) * 4608;                     \
    unsigned short* vd_ = vlds + (BUF) * 4608;                     \
    *(uint4*)kd_ = kr0;  *(uint4*)(kd_ + 8) = kr1;                 \
    *(uint4*)vd_ = vr0;  *(uint4*)(vd_ + 8) = vr1;                 \
  } while (0)

  ISSUE(0);
  STWRITE(0);
  ISSUE(1);
  __syncthreads();

  const f4 fz = {0.f, 0.f, 0.f, 0.f};
  f4 ao[2][4], aol[2];
#pragma unroll
  for (int mr = 0; mr < 2; mr++) {
    aol[mr] = fz;
#pragma unroll
    for (int i = 0; i < 4; i++) ao[mr][i] = fz;
  }
  const short on = (short)0x3F80;                  // bf16 1.0
  const bf8 onesf = {on, on, on, on, on, on, on, on};
  const float* confb = conf + b * NSP;

#pragma unroll 2
  for (int t = 0; t < 13; t++) {
    const int cur = t & 1;
    const unsigned short* KtB = &Kt[cur][0];
    const unsigned short* VtB = &Vt[cur][0];
    // QK^T, mf-major with transient K frags; conf folded into first-layer C-init.
    // s_[2][4]: lane holds q=l15, kv=16mf+4g+reg for both q-groups.
    f4 s_[2][4];
#pragma unroll
    for (int mf = 0; mf < 4; mf++) {
      float4 cv = *(const float4*)(confb + t * 64 + 16 * mf + 4 * g);
      f4 c0; c0[0] = cv.x; c0[1] = cv.y; c0[2] = cv.z; c0[3] = cv.w;
      bf8 kf0 = ldfrag(KtB, 72, 16 * mf, 0);
      s_[0][mf] = MFMA16(kf0, qf[0][0], c0);
      s_[1][mf] = MFMA16(kf0, qf[1][0], c0);
    }
#pragma unroll
    for (int mf = 0; mf < 4; mf++) {
      bf8 kf1 = ldfrag(KtB, 72, 16 * mf, 32);
      s_[0][mf] = MFMA16(kf1, qf[0][1], s_[0][mf]);
      s_[1][mf] = MFMA16(kf1, qf[1][1], s_[1][mf]);
    }
#pragma unroll
    for (int mr = 0; mr < 2; mr++) {
      unsigned W[4][2];
#pragma unroll
      for (int mf = 0; mf < 4; mf++) {
        float p0 = EXP2(s_[mr][mf][0]);
        float p1 = EXP2(s_[mr][mf][1]);
        float p2 = EXP2(s_[mr][mf][2]);
        float p3 = EXP2(s_[mr][mf][3]);
        W[mf][0] = pk2(p0, p1);
        W[mf][1] = pk2(p2, p3);
      }
      // PV with just-in-time V-frags: keeps V out of the resident register set
#pragma unroll
      for (int ks = 0; ks < 2; ks++) {
        bf8 pa = rows2frag(W[2 * ks], W[2 * ks + 1]);
        aol[mr] = MFMA16(pa, onesf, aol[mr]);
#pragma unroll
        for (int nfd = 0; nfd < 4; nfd++) {
          bf8 vf = ldfrag(VtB, 72, 16 * nfd, 32 * ks);
          ao[mr][nfd] = MFMA16(pa, vf, ao[mr][nfd]);
        }
      }
    }
    if (t < 12) STWRITE(cur ^ 1);
    if (t < 11) ISSUE(t + 2);
    __syncthreads();
  }
#undef ISSUE
#undef STWRITE
#pragma unroll
  for (int mr = 0; mr < 2; mr++) {
    float inv[4];
#pragma unroll
    for (int reg = 0; reg < 4; reg++) inv[reg] = 1.0f / aol[mr][reg];
#pragma unroll
    for (int nfd = 0; nfd < 4; nfd++)
#pragma unroll
      for (int reg = 0; reg < 4; reg++) {
        int n = q0 + 16 * mr + 4 * g + reg;
        int col = h * 64 + 16 * nfd + l15;
        attbuf[((long)b * NQTOK + n) * 128 + col] = f2b(ao[mr][nfd][reg] * inv[reg]);
      }
  }
}

// ---------------- final projection (A+B staged, XCD-swizzled per batch) ----------------
__launch_bounds__(256)
__global__ void k_proj(const unsigned short* __restrict__ attbuf,
                       const unsigned short* __restrict__ pwt,
                       const float* __restrict__ pb, float* __restrict__ out) {
  __shared__ unsigned short At[64 * 136];
  __shared__ unsigned short Bt[128 * 136];
  const int tid = threadIdx.x;
  const int lane = tid & 63, w = tid >> 6;
  const int l15 = lane & 15, g = lane >> 4;
  const int bid = blockIdx.x;
  const int r0 = (bid & 7) * NQTOK + (bid >> 3) * 64;   // batch (bid&7) on XCD (bid&7)
#pragma unroll
  for (int j = 0; j < 4; j++) {
    int id = tid + 256 * j;
    int row = id >> 4, c0 = (id & 15) << 3;
    *(uint4*)(At + row * 136 + c0) = *(const uint4*)(attbuf + (long)(r0 + row) * 128 + c0);
  }
#pragma unroll
  for (int j = 0; j < 8; j++) {
    int id = tid + 256 * j;
    int row = id >> 4, c0 = (id & 15) << 3;
    *(uint4*)(Bt + row * 136 + c0) = *(const uint4*)(pwt + (long)row * 128 + c0);
  }
  __syncthreads();
  const f4 fz = {0.f, 0.f, 0.f, 0.f};
  f4 acc[8];
#pragma unroll
  for (int i = 0; i < 8; i++) acc[i] = fz;
#pragma unroll
  for (int ks = 0; ks < 4; ks++) {
    bf8 a = ldfrag(At, 136, 16 * w, 32 * ks);
#pragma unroll
    for (int nf = 0; nf < 8; nf++) {
      bf8 bb = ldfrag(Bt, 136, 16 * nf, 32 * ks);
      acc[nf] = MFMA16(a, bb, acc[nf]);
    }
  }
#pragma unroll
  for (int nf = 0; nf < 8; nf++) {
    float bias = pb[16 * nf + l15];
#pragma unroll
    for (int reg = 0; reg < 4; reg++) {
      int r = r0 + 16 * w + 4 * g + reg;
      out[(long)r * 128 + 16 * nf + l15] = acc[nf][reg] + bias;
    }
  }
}

extern "C" void kernel_launch(void* const* d_in, const int* in_sizes, int n_in,
                              void* d_out, int out_size, void* d_ws, size_t ws_size,
                              hipStream_t stream) {
  const float* q_x  = (const float*)d_in[0];
  const float* kv_x = (const float*)d_in[1];
  const float* tsc  = (const float*)d_in[2];
  const int*   idxt = (const int*)d_in[3];
  const float* q_w  = (const float*)d_in[8];
  const float* kv_w = (const float*)d_in[9];
  const float* pw   = (const float*)d_in[10];
  const float* pb   = (const float*)d_in[11];
  const float* srw  = (const float*)d_in[12];
  const float* srb  = (const float*)d_in[13];
  const float* ng   = (const float*)d_in[14];
  const float* nb   = (const float*)d_in[15];
  float* outp = (float*)d_out;

  char* ws = (char*)d_ws;
  size_t off = 0;
  auto take = [&](size_t bytes) {
    char* p = ws + off;
    off += (bytes + 255) & ~(size_t)255;
    return p;
  };
  unsigned short* qwt   = (unsigned short*)take(128 * 128 * 2);
  unsigned short* pwt   = (unsigned short*)take(128 * 128 * 2);
  unsigned short* kvwt  = (unsigned short*)take(256 * 128 * 2);
  unsigned short* srwt  = (unsigned short*)take(128 * 2048 * 2);
  unsigned short* kvmap = (unsigned short*)take((size_t)NBATCH * 12544 * 128 * 2);
  float* conf_map       = (float*)take((size_t)NBATCH * 12544 * 4);
  unsigned short* kbuf  = (unsigned short*)take((size_t)NBATCH * 2 * NSP * 64 * 2);
  unsigned short* vbuf  = (unsigned short*)take((size_t)NBATCH * 2 * NSP * 64 * 2);
  float* conf           = (float*)take((size_t)NBATCH * NSP * 4);
  unsigned short* qbuf  = (unsigned short*)take((size_t)NBATCH * 2 * NQTOK * 64 * 2);
  unsigned short* attbuf = kvmap;  // kv_map dead after k_conv_ln_kv

  k_token2map<<<12800, 256, 0, stream>>>(kv_x, tsc, idxt, kvmap, conf_map,
                                         q_w, kv_w, pw, srw, qwt, kvwt, pwt, srwt,
                                         (unsigned*)kbuf, (unsigned*)vbuf, conf);
  k_conv_ln_kv<<<98, 256, 0, stream>>>(kvmap, srwt, srb, ng, nb, kvwt, kbuf, vbuf,
                                       conf_map, conf);
  k_q<<<1568, 256, 0, stream>>>(q_x, qwt, qbuf);
  k_attn<<<1568, 256, 0, stream>>>(qbuf, kbuf, vbuf, conf, attbuf);
  k_proj<<<1568, 256, 0, stream>>>(attbuf, pwt, pb, outp);
}